// Round 12
// baseline (432.748 us; speedup 1.0000x reference)
//
#include <hip/hip_runtime.h>
#include <math.h>

#define NN 50000
#define EE 800000
#define GG 256
#define NPB 100          // nodes per bucket (<128 so local idx fits in 7 bits)
#define NBUCK 500        // NN / NPB exactly
#define EPB 4096         // edges per block chunk (hist/scatter)
#define NEB 196          // ceil(EE/EPB)
#define NB_NODE 196      // ceil(NN/256) node-parallel grids

__device__ __forceinline__ float gelu_f(float v){
    return 0.5f * v * (1.0f + erff(v * 0.70710678118654752f));
}

// ---------------- bucket histogram of dst (LDS-privatized, padded global) ----------------
__global__ __launch_bounds__(256) void k_hist(const int* __restrict__ dst, int* __restrict__ bucket_cnt_p, int e){
    __shared__ int hist[512];
    int t = threadIdx.x;
    int start = blockIdx.x * EPB;
    for (int k = t; k < 512; k += 256) hist[k] = 0;
    __syncthreads();
#pragma unroll
    for (int k = 0; k < EPB / 256; k++){
        int idx = start + k * 256 + t;
        if (idx < e) atomicAdd(&hist[dst[idx] / NPB], 1);
    }
    __syncthreads();
    for (int k = t; k < NBUCK; k += 256){
        int h = hist[k];
        if (h) atomicAdd(&bucket_cnt_p[k * 16], h);   // *16: one cache line per bucket
    }
}

// ---------------- scan bucket counts -> offsets + scatter cursors ----------------
__global__ __launch_bounds__(512) void k_bscan(const int* __restrict__ bucket_cnt_p,
                                               int* __restrict__ bucket_off, int* __restrict__ cursor_p){
    __shared__ int s[512];
    int t = threadIdx.x;
    int v = (t < NBUCK) ? bucket_cnt_p[t * 16] : 0;
    s[t] = v;
    __syncthreads();
    for (int off = 1; off < 512; off <<= 1){
        int u = (t >= off) ? s[t - off] : 0;
        __syncthreads();
        s[t] += u;
        __syncthreads();
    }
    if (t < NBUCK){
        int ex = s[t] - v;
        bucket_off[t] = ex;
        cursor_p[t * 16] = ex;
    }
}

// ---------------- partition packed (src<<7 | dst%NPB) into bucket-contiguous ebuf ----------------
__global__ __launch_bounds__(256) void k_scatter(const int* __restrict__ src, const int* __restrict__ dst,
                                                 int* __restrict__ cursor_p, int* __restrict__ ebuf, int e){
    __shared__ int hist[512], base[512];
    int t = threadIdx.x;
    int start = blockIdx.x * EPB;
    for (int k = t; k < 512; k += 256) hist[k] = 0;
    __syncthreads();
    int pk[EPB / 256], bb[EPB / 256];
    int cntl = 0;
#pragma unroll
    for (int k = 0; k < EPB / 256; k++){
        int idx = start + k * 256 + t;
        if (idx < e){
            int s_ = src[idx], d_ = dst[idx];
            int b_ = d_ / NPB;
            pk[cntl] = (s_ << 7) | (d_ - b_ * NPB);
            bb[cntl] = b_;
            atomicAdd(&hist[b_], 1);
            cntl++;
        }
    }
    __syncthreads();
    for (int k = t; k < NBUCK; k += 256){
        int h = hist[k];
        base[k] = h ? atomicAdd(&cursor_p[k * 16], h) : 0;
    }
    __syncthreads();
    for (int k = t; k < 512; k += 256) hist[k] = 0;
    __syncthreads();
    for (int k = 0; k < cntl; k++){
        int b_ = bb[k];
        int pos = base[b_] + atomicAdd(&hist[b_], 1);
        ebuf[pos] = pk[k];
    }
}

// ---------------- per-bucket CSR finalize: rp/col + dis/invdis/xd (LDS only) ----------------
__global__ __launch_bounds__(256) void k_build(const int* __restrict__ ebuf,
                                               const int* __restrict__ bucket_cnt_p,
                                               const int* __restrict__ bucket_off,
                                               int* __restrict__ rp, int* __restrict__ col,
                                               float* __restrict__ dis, float* __restrict__ invdis,
                                               float2* __restrict__ xd,
                                               const float* __restrict__ x, int n){
    int b = blockIdx.x;
    int t = threadIdx.x;
    int nbase = b * NPB;
    int eoff = bucket_off[b];
    int ecnt = bucket_cnt_p[b * 16];
    __shared__ int cnt[128], excl[128], cnt2[128], s[128];
    if (t < 128){ cnt[t] = 0; cnt2[t] = 0; }
    __syncthreads();
    for (int j = t; j < ecnt; j += 256)
        atomicAdd(&cnt[ebuf[eoff + j] & 127], 1);
    __syncthreads();
    int v = (t < 128) ? cnt[t] : 0;
    if (t < 128) s[t] = v;
    __syncthreads();
    for (int off = 1; off < 128; off <<= 1){
        int u = (t < 128 && t >= off) ? s[t - off] : 0;
        __syncthreads();
        if (t < 128) s[t] += u;
        __syncthreads();
    }
    if (t < 128) excl[t] = s[t] - v;
    __syncthreads();
    if (t < NPB){
        int node = nbase + t;      // NBUCK*NPB == NN exactly
        int dgg = cnt[t];
        rp[node] = eoff + excl[t];
        float dv = rsqrtf((float)(dgg + 1));   // +1 self loop
        dis[node] = dv;
        invdis[node] = sqrtf((float)(dgg + 1));
        xd[node] = make_float2(dv * x[node], dv);   // (xs, dis) packed
    }
    if (b == NBUCK - 1 && t == 0) rp[n] = eoff + ecnt;   // == E
    __syncthreads();
    for (int j = t; j < ecnt; j += 256){
        int v2 = ebuf[eoff + j];
        int li = v2 & 127;
        int p = eoff + excl[li] + atomicAdd(&cnt2[li], 1);
        col[p] = v2 >> 7;          // 6.4KB window per bucket -> full line reuse
    }
}

// ---------------- fused: CSR walk (agg xs, dsum) + layer-1 1->16 linear+GELU+prescale ----------------
__global__ __launch_bounds__(256) void k_g1l1(const float2* __restrict__ xd,
                                              const int* __restrict__ rp, const int* __restrict__ col,
                                              const float* __restrict__ W, const float* __restrict__ bias,
                                              float* __restrict__ dsum, float* __restrict__ hs, int n){
    int node = blockIdx.x * 256 + threadIdx.x;
    if (node >= n) return;
    int beg = rp[node], end = rp[node + 1];
    float a0 = 0.f, a1 = 0.f, d0 = 0.f, d1 = 0.f;
    int j = beg;
    for (; j + 1 < end; j += 2){
        float2 v0 = xd[col[j]];
        float2 v1 = xd[col[j + 1]];
        a0 += v0.x; d0 += v0.y;
        a1 += v1.x; d1 += v1.y;
    }
    if (j < end){ float2 v0 = xd[col[j]]; a0 += v0.x; d0 += v0.y; }
    float2 self = xd[node];
    float dn = self.y;
    dsum[node] = d0 + d1 + dn;
    float a = dn * (a0 + a1 + self.x);
    float4* o = (float4*)(hs + (size_t)node * 16);
#pragma unroll
    for (int u = 0; u < 4; u++){
        float4 r;
        r.x = gelu_f(bias[u*4+0] + a * W[u*4+0]) * dn;
        r.y = gelu_f(bias[u*4+1] + a * W[u*4+1]) * dn;
        r.z = gelu_f(bias[u*4+2] + a * W[u*4+2]) * dn;
        r.w = gelu_f(bias[u*4+3] + a * W[u*4+3]) * dn;
        o[u] = r;
    }
}

// ---------------- gather of pre-scaled hs with inline BN affine (float4, 8-edge unroll) ----------------
template<int C>
__global__ __launch_bounds__(256) void k_gather(const float* __restrict__ hs, const int* __restrict__ rp,
                                                const int* __restrict__ col, const float* __restrict__ dis,
                                                const float* __restrict__ dsum, const float* __restrict__ stat,
                                                const float* __restrict__ gamma, const float* __restrict__ beta,
                                                float* __restrict__ outp, int n){
    constexpr int TPN = C / 4;
    int i = blockIdx.x * 256 + threadIdx.x;
    int node = i / TPN, q = i % TPN;
    if (node >= n) return;
    int c0 = q * 4;
    const float invn = 1.0f / (float)NN;
    float scv[4], shv[4];
#pragma unroll
    for (int u = 0; u < 4; u++){
        float mean = stat[c0 + u] * invn;
        float var  = stat[128 + c0 + u] * invn - mean * mean;
        float sc   = gamma[c0 + u] * rsqrtf(var + 1e-5f);
        scv[u] = sc;
        shv[u] = beta[c0 + u] - mean * sc;
    }
    const float4* h4 = (const float4*)hs;
    int beg = rp[node], end = rp[node + 1];
    float a0 = 0.f, a1 = 0.f, a2 = 0.f, a3 = 0.f;
    float b0 = 0.f, b1 = 0.f, b2 = 0.f, b3 = 0.f;
    int j = beg;
    for (; j + 7 < end; j += 8){
        int i0 = col[j],   i1 = col[j+1], i2 = col[j+2], i3 = col[j+3];
        int i4 = col[j+4], i5 = col[j+5], i6 = col[j+6], i7 = col[j+7];
        float4 v0 = h4[i0 * TPN + q];
        float4 v1 = h4[i1 * TPN + q];
        float4 v2 = h4[i2 * TPN + q];
        float4 v3 = h4[i3 * TPN + q];
        float4 v4 = h4[i4 * TPN + q];
        float4 v5 = h4[i5 * TPN + q];
        float4 v6 = h4[i6 * TPN + q];
        float4 v7 = h4[i7 * TPN + q];
        a0 += v0.x; a1 += v0.y; a2 += v0.z; a3 += v0.w;
        b0 += v1.x; b1 += v1.y; b2 += v1.z; b3 += v1.w;
        a0 += v2.x; a1 += v2.y; a2 += v2.z; a3 += v2.w;
        b0 += v3.x; b1 += v3.y; b2 += v3.z; b3 += v3.w;
        a0 += v4.x; a1 += v4.y; a2 += v4.z; a3 += v4.w;
        b0 += v5.x; b1 += v5.y; b2 += v5.z; b3 += v5.w;
        a0 += v6.x; a1 += v6.y; a2 += v6.z; a3 += v6.w;
        b0 += v7.x; b1 += v7.y; b2 += v7.z; b3 += v7.w;
    }
    for (; j < end; j++){
        float4 v = h4[col[j] * TPN + q];
        a0 += v.x; a1 += v.y; a2 += v.z; a3 += v.w;
    }
    float4 vs = h4[node * TPN + q];    // self loop (weight 1 in pre-scaled space)
    a0 += vs.x; a1 += vs.y; a2 += vs.z; a3 += vs.w;
    a0 += b0; a1 += b1; a2 += b2; a3 += b3;
    float dn = dis[node];
    float dsm = dsum[node];
    float4 r = make_float4((a0 * scv[0] + shv[0] * dsm) * dn,
                           (a1 * scv[1] + shv[1] * dsm) * dn,
                           (a2 * scv[2] + shv[2] * dsm) * dn,
                           (a3 * scv[3] + shv[3] * dsm) * dn);
    ((float4*)outp)[node * TPN + q] = r;
}

// ---------------- dense linear + bias + GELU: 4 nodes x 4 channels per thread ----------------
template<int CIN, int COUT, bool SCALE>
__global__ __launch_bounds__(256) void k_linT(const float* __restrict__ xin, const float* __restrict__ dis,
                                              const float* __restrict__ W,
                                              const float* __restrict__ bias, float* __restrict__ outp, int n){
    constexpr int QC = COUT / 4;
    constexpr int K4 = CIN / 4;
    int i = blockIdx.x * 256 + threadIdx.x;
    int tile = i / QC, q = i % QC;
    int n0 = tile * 4;                 // NN % 4 == 0
    if (n0 >= n) return;
    const float4* xp0 = (const float4*)(xin + (size_t)(n0 + 0) * CIN);
    const float4* xp1 = (const float4*)(xin + (size_t)(n0 + 1) * CIN);
    const float4* xp2 = (const float4*)(xin + (size_t)(n0 + 2) * CIN);
    const float4* xp3 = (const float4*)(xin + (size_t)(n0 + 3) * CIN);
    const float4* Wq = (const float4*)W + q;      // row k at Wq[k * QC]
    float4 bb = ((const float4*)bias)[q];
    float acc[4][4];
#pragma unroll
    for (int nd = 0; nd < 4; nd++){
        acc[nd][0] = bb.x; acc[nd][1] = bb.y; acc[nd][2] = bb.z; acc[nd][3] = bb.w;
    }
#pragma unroll 1
    for (int k4 = 0; k4 < K4; k4++){
        float4 xv[4];
        xv[0] = xp0[k4]; xv[1] = xp1[k4]; xv[2] = xp2[k4]; xv[3] = xp3[k4];
        float4 w0 = Wq[(k4 * 4 + 0) * QC];
        float4 w1 = Wq[(k4 * 4 + 1) * QC];
        float4 w2 = Wq[(k4 * 4 + 2) * QC];
        float4 w3 = Wq[(k4 * 4 + 3) * QC];
#pragma unroll
        for (int nd = 0; nd < 4; nd++){
            acc[nd][0] += xv[nd].x*w0.x + xv[nd].y*w1.x + xv[nd].z*w2.x + xv[nd].w*w3.x;
            acc[nd][1] += xv[nd].x*w0.y + xv[nd].y*w1.y + xv[nd].z*w2.y + xv[nd].w*w3.y;
            acc[nd][2] += xv[nd].x*w0.z + xv[nd].y*w1.z + xv[nd].z*w2.z + xv[nd].w*w3.z;
            acc[nd][3] += xv[nd].x*w0.w + xv[nd].y*w1.w + xv[nd].z*w2.w + xv[nd].w*w3.w;
        }
    }
    float4* o4 = (float4*)outp;
#pragma unroll
    for (int nd = 0; nd < 4; nd++){
        float sc = SCALE ? dis[n0 + nd] : 1.0f;
        o4[(size_t)(n0 + nd) * QC + q] =
            make_float4(gelu_f(acc[nd][0])*sc, gelu_f(acc[nd][1])*sc,
                        gelu_f(acc[nd][2])*sc, gelu_f(acc[nd][3])*sc);
    }
}

// ---------------- fused layer-4 GEMM + mean-pool: one block per graph ----------------
// W4 column in registers (64 f); node rows are wave-uniform loads (broadcast/L1).
// Two halves of the block process alternating nodes; LDS reduce at the end.
__global__ __launch_bounds__(256) void k_l4p(const float* __restrict__ abuf, const float* __restrict__ W,
                                             const float* __restrict__ bias, const int* __restrict__ batch,
                                             float* __restrict__ pool, int n){
    int g = blockIdx.x;
    int t = threadIdx.x;
    int half = t >> 7;
    int c = t & 127;
    int lo = 0, hi = n;
    while (lo < hi){ int m = (lo + hi) >> 1; if (batch[m] < g) lo = m + 1; else hi = m; }
    int s = lo;
    hi = n;
    while (lo < hi){ int m = (lo + hi) >> 1; if (batch[m] < g + 1) lo = m + 1; else hi = m; }
    int e = lo;
    float wcol[64];
#pragma unroll
    for (int k = 0; k < 64; k++) wcol[k] = W[k * 128 + c];
    float b = bias[c];
    float acc = 0.f;
    for (int node = s + half; node < e; node += 2){
        const float4* row = (const float4*)(abuf + (size_t)node * 64);
        float dot = b;
#pragma unroll
        for (int k4 = 0; k4 < 16; k4++){
            float4 xv = row[k4];
            dot += xv.x*wcol[k4*4+0] + xv.y*wcol[k4*4+1] + xv.z*wcol[k4*4+2] + xv.w*wcol[k4*4+3];
        }
        acc += gelu_f(dot);
    }
    __shared__ float red[256];
    red[t] = acc;
    __syncthreads();
    if (t < 128){
        float sum = red[t] + red[t + 128];
        pool[g * 128 + t] = sum / fmaxf((float)(e - s), 1.0f);
    }
}

// ---------------- BN stats over raw h (de-scale pre-scaled hs by invdis) ----------------
template<int C>
__global__ __launch_bounds__(256) void k_stats(const float* __restrict__ hs, const float* __restrict__ invdis,
                                               float* __restrict__ stat, int n){
    constexpr int REP = 256 / C;
    int t = threadIdx.x;
    int rep = t / C;
    int c = t % C;
    float s = 0.f, q = 0.f;
    for (int row = blockIdx.x * REP + rep; row < n; row += gridDim.x * REP){
        float v = hs[(long long)row * C + c] * invdis[row];
        s += v; q += v * v;
    }
    __shared__ float ss[256], sq[256];
    ss[t] = s; sq[t] = q;
    __syncthreads();
    for (int off = 128; off >= C; off >>= 1){
        if (t < off){ ss[t] += ss[t + off]; sq[t] += sq[t + off]; }
        __syncthreads();
    }
    if (t < C){
        atomicAdd(&stat[t], ss[t]);
        atomicAdd(&stat[128 + t], sq[t]);
    }
}

// ---------------- MLP head: 256 graphs, one block each ----------------
__global__ __launch_bounds__(128) void k_mlp(const float* __restrict__ pool,
                                             const float* __restrict__ yex,
                                             const float* __restrict__ lw1, const float* __restrict__ lb1,
                                             const float* __restrict__ lw2, const float* __restrict__ lb2,
                                             const float* __restrict__ lw3, const float* __restrict__ lb3,
                                             const float* __restrict__ lw4, const float* __restrict__ lb4,
                                             float* __restrict__ outp){
    int g = blockIdx.x;
    int t = threadIdx.x;
    __shared__ float z[136];
    __shared__ float z2[128];
    __shared__ float z3[64];
    __shared__ float z4[32];
    z[t] = pool[g * 128 + t];
    if (t < 7) z[128 + t] = yex[g * 7 + t];
    __syncthreads();
    {   // 135 -> 128
        float acc = lb1[t];
        for (int k = 0; k < 135; k++) acc += z[k] * lw1[k * 128 + t];
        z2[t] = gelu_f(acc);
    }
    __syncthreads();
    if (t < 64){   // 128 -> 64
        float acc = lb2[t];
        for (int k = 0; k < 128; k++) acc += z2[k] * lw2[k * 64 + t];
        z3[t] = gelu_f(acc);
    }
    __syncthreads();
    if (t < 32){   // 64 -> 32
        float acc = lb3[t];
        for (int k = 0; k < 64; k++) acc += z3[k] * lw3[k * 32 + t];
        z4[t] = gelu_f(acc);
    }
    __syncthreads();
    if (t < 2){    // 32 -> 2, sigmoid
        float acc = lb4[t];
        for (int k = 0; k < 32; k++) acc += z4[k] * lw4[k * 2 + t];
        outp[g * 2 + t] = 1.0f / (1.0f + expf(-acc));
    }
}

extern "C" void kernel_launch(void* const* d_in, const int* in_sizes, int n_in,
                              void* d_out, int out_size, void* d_ws, size_t ws_size,
                              hipStream_t stream) {
    const float* x     = (const float*)d_in[0];
    const int*   ei    = (const int*)  d_in[1];   // [2, E]: src = ei, dst = ei+E
    const int*   batch = (const int*)  d_in[2];
    const float* yex   = (const float*)d_in[3];
    const float* W1 = (const float*)d_in[4];  const float* b1 = (const float*)d_in[5];
    const float* W2 = (const float*)d_in[6];  const float* b2 = (const float*)d_in[7];
    const float* W3 = (const float*)d_in[8];  const float* b3 = (const float*)d_in[9];
    const float* W4 = (const float*)d_in[10]; const float* b4 = (const float*)d_in[11];
    const float* g1 = (const float*)d_in[12]; const float* be1 = (const float*)d_in[13];
    const float* g2 = (const float*)d_in[14]; const float* be2 = (const float*)d_in[15];
    const float* g3 = (const float*)d_in[16]; const float* be3 = (const float*)d_in[17];
    const float* lw1 = (const float*)d_in[18]; const float* lb1 = (const float*)d_in[19];
    const float* lw2 = (const float*)d_in[20]; const float* lb2 = (const float*)d_in[21];
    const float* lw3 = (const float*)d_in[22]; const float* lb3 = (const float*)d_in[23];
    const float* lw4 = (const float*)d_in[24]; const float* lb4 = (const float*)d_in[25];
    float* out = (float*)d_out;

    // ---- workspace carve (256B-aligned); zero-region first ----
    char* wsb = (char*)d_ws;
    size_t off = 0;
    auto alloc = [&](size_t elems) -> void* {
        void* p = wsb + off;
        off += ((elems * 4 + 255) / 256) * 256;
        return p;
    };
    float* stats        = (float*)alloc(3 * 256);      // layer l: [l*256+c]=sum, [+128]=sumsq
    int*   bucket_cnt_p = (int*)  alloc(NBUCK * 16);   // padded: 1 line per bucket
    size_t zero_bytes = off;
    int*   bucket_off   = (int*)  alloc(NBUCK);
    int*   cursor_p     = (int*)  alloc(NBUCK * 16);
    int*   ebuf         = (int*)  alloc(EE);           // packed (src<<7 | dst%NPB)
    float* pool   = (float*)alloc(GG * 128);
    int*   rp     = (int*)  alloc(NN + 1);
    float* dis    = (float*)alloc(NN);
    float* invdis = (float*)alloc(NN);
    float* dsum   = (float*)alloc(NN);
    float2* xd    = (float2*)alloc(NN * 2);            // (xs, dis) packed
    int*   col    = (int*)  alloc(EE);
    float* hbuf   = (float*)alloc((size_t)NN * 64);   // hs (16/32/64 ch)
    float* abuf   = (float*)alloc((size_t)NN * 64);   // aggregated conv inputs (<=64 ch)

    hipMemsetAsync(d_ws, 0, zero_bytes, stream);

    auto nb = [](long long total){ return (int)((total + 255) / 256); };

    // ---- CSR build via LDS-binned radix partition (no global random scatter) ----
    k_hist   <<<NEB, 256, 0, stream>>>(ei + EE, bucket_cnt_p, EE);
    k_bscan  <<<1, 512, 0, stream>>>(bucket_cnt_p, bucket_off, cursor_p);
    k_scatter<<<NEB, 256, 0, stream>>>(ei, ei + EE, cursor_p, ebuf, EE);
    k_build  <<<NBUCK, 256, 0, stream>>>(ebuf, bucket_cnt_p, bucket_off, rp, col, dis, invdis, xd, x, NN);

    // ---- layer 1: fused CSR-walk (agg xs + dsum) + 1->16 linear+gelu (pre-scaled), stats ----
    k_g1l1<<<NB_NODE, 256, 0, stream>>>(xd, rp, col, W1, b1, dsum, hbuf, NN);
    k_stats<16><<<128, 256, 0, stream>>>(hbuf, invdis, stats + 0, NN);

    // ---- layer 2: gather hs1 (BN1 inline), 16->32 linear+gelu (pre-scaled), stats ----
    k_gather<16><<<nb((long long)NN * 4), 256, 0, stream>>>(hbuf, rp, col, dis, dsum, stats + 0, g1, be1, abuf, NN);
    k_linT<16, 32, true><<<nb((long long)(NN / 4) * 8), 256, 0, stream>>>(abuf, dis, W2, b2, hbuf, NN);
    k_stats<32><<<128, 256, 0, stream>>>(hbuf, invdis, stats + 256, NN);

    // ---- layer 3: gather hs2 (BN2 inline), 32->64 linear+gelu (pre-scaled), stats ----
    k_gather<32><<<nb((long long)NN * 8), 256, 0, stream>>>(hbuf, rp, col, dis, dsum, stats + 256, g2, be2, abuf, NN);
    k_linT<32, 64, true><<<nb((long long)(NN / 4) * 16), 256, 0, stream>>>(abuf, dis, W3, b3, hbuf, NN);
    k_stats<64><<<128, 256, 0, stream>>>(hbuf, invdis, stats + 512, NN);

    // ---- layer 4: gather hs3 (BN3 inline), fused 64->128 GEMM + mean-pool (no h4 buffer) ----
    k_gather<64><<<nb((long long)NN * 16), 256, 0, stream>>>(hbuf, rp, col, dis, dsum, stats + 512, g3, be3, abuf, NN);
    k_l4p<<<GG, 256, 0, stream>>>(abuf, W4, b4, batch, pool, NN);

    // ---- MLP head ----
    k_mlp<<<GG, 128, 0, stream>>>(pool, yex,
                                  lw1, lb1, lw2, lb2, lw3, lb3, lw4, lb4, out);
}

// Round 13
// 363.012 us; speedup vs baseline: 1.1921x; 1.1921x over previous
//
#include <hip/hip_runtime.h>
#include <math.h>

#define NN 50000
#define EE 800000
#define GG 256
#define NPB 100          // nodes per bucket (<128 so local idx fits in 7 bits)
#define NBUCK 500        // NN / NPB exactly
#define EPB 4096         // edges per block chunk (hist/scatter)
#define NEB 196          // ceil(EE/EPB)
#define NB_NODE 196      // ceil(NN/256) node-parallel grids

__device__ __forceinline__ float gelu_f(float v){
    return 0.5f * v * (1.0f + erff(v * 0.70710678118654752f));
}

// ---------------- bucket histogram of dst (LDS-privatized, padded global) ----------------
__global__ __launch_bounds__(256) void k_hist(const int* __restrict__ dst, int* __restrict__ bucket_cnt_p, int e){
    __shared__ int hist[512];
    int t = threadIdx.x;
    int start = blockIdx.x * EPB;
    for (int k = t; k < 512; k += 256) hist[k] = 0;
    __syncthreads();
#pragma unroll
    for (int k = 0; k < EPB / 256; k++){
        int idx = start + k * 256 + t;
        if (idx < e) atomicAdd(&hist[dst[idx] / NPB], 1);
    }
    __syncthreads();
    for (int k = t; k < NBUCK; k += 256){
        int h = hist[k];
        if (h) atomicAdd(&bucket_cnt_p[k * 16], h);   // *16: one cache line per bucket
    }
}

// ---------------- scan bucket counts -> offsets + scatter cursors ----------------
__global__ __launch_bounds__(512) void k_bscan(const int* __restrict__ bucket_cnt_p,
                                               int* __restrict__ bucket_off, int* __restrict__ cursor_p){
    __shared__ int s[512];
    int t = threadIdx.x;
    int v = (t < NBUCK) ? bucket_cnt_p[t * 16] : 0;
    s[t] = v;
    __syncthreads();
    for (int off = 1; off < 512; off <<= 1){
        int u = (t >= off) ? s[t - off] : 0;
        __syncthreads();
        s[t] += u;
        __syncthreads();
    }
    if (t < NBUCK){
        int ex = s[t] - v;
        bucket_off[t] = ex;
        cursor_p[t * 16] = ex;
    }
}

// ---------------- partition packed (src<<7 | dst%NPB) into bucket-contiguous ebuf ----------------
__global__ __launch_bounds__(256) void k_scatter(const int* __restrict__ src, const int* __restrict__ dst,
                                                 int* __restrict__ cursor_p, int* __restrict__ ebuf, int e){
    __shared__ int hist[512], base[512];
    int t = threadIdx.x;
    int start = blockIdx.x * EPB;
    for (int k = t; k < 512; k += 256) hist[k] = 0;
    __syncthreads();
    int pk[EPB / 256], bb[EPB / 256];
    int cntl = 0;
#pragma unroll
    for (int k = 0; k < EPB / 256; k++){
        int idx = start + k * 256 + t;
        if (idx < e){
            int s_ = src[idx], d_ = dst[idx];
            int b_ = d_ / NPB;
            pk[cntl] = (s_ << 7) | (d_ - b_ * NPB);
            bb[cntl] = b_;
            atomicAdd(&hist[b_], 1);
            cntl++;
        }
    }
    __syncthreads();
    for (int k = t; k < NBUCK; k += 256){
        int h = hist[k];
        base[k] = h ? atomicAdd(&cursor_p[k * 16], h) : 0;
    }
    __syncthreads();
    for (int k = t; k < 512; k += 256) hist[k] = 0;
    __syncthreads();
    for (int k = 0; k < cntl; k++){
        int b_ = bb[k];
        int pos = base[b_] + atomicAdd(&hist[b_], 1);
        ebuf[pos] = pk[k];
    }
}

// ---------------- per-bucket CSR finalize: rp/col + dis/invdis/xd (LDS only) ----------------
__global__ __launch_bounds__(256) void k_build(const int* __restrict__ ebuf,
                                               const int* __restrict__ bucket_cnt_p,
                                               const int* __restrict__ bucket_off,
                                               int* __restrict__ rp, int* __restrict__ col,
                                               float* __restrict__ dis, float* __restrict__ invdis,
                                               float2* __restrict__ xd,
                                               const float* __restrict__ x, int n){
    int b = blockIdx.x;
    int t = threadIdx.x;
    int nbase = b * NPB;
    int eoff = bucket_off[b];
    int ecnt = bucket_cnt_p[b * 16];
    __shared__ int cnt[128], excl[128], cnt2[128], s[128];
    if (t < 128){ cnt[t] = 0; cnt2[t] = 0; }
    __syncthreads();
    for (int j = t; j < ecnt; j += 256)
        atomicAdd(&cnt[ebuf[eoff + j] & 127], 1);
    __syncthreads();
    int v = (t < 128) ? cnt[t] : 0;
    if (t < 128) s[t] = v;
    __syncthreads();
    for (int off = 1; off < 128; off <<= 1){
        int u = (t < 128 && t >= off) ? s[t - off] : 0;
        __syncthreads();
        if (t < 128) s[t] += u;
        __syncthreads();
    }
    if (t < 128) excl[t] = s[t] - v;
    __syncthreads();
    if (t < NPB){
        int node = nbase + t;      // NBUCK*NPB == NN exactly
        int dgg = cnt[t];
        rp[node] = eoff + excl[t];
        float dv = rsqrtf((float)(dgg + 1));   // +1 self loop
        dis[node] = dv;
        invdis[node] = sqrtf((float)(dgg + 1));
        xd[node] = make_float2(dv * x[node], dv);   // (xs, dis) packed
    }
    if (b == NBUCK - 1 && t == 0) rp[n] = eoff + ecnt;   // == E
    __syncthreads();
    for (int j = t; j < ecnt; j += 256){
        int v2 = ebuf[eoff + j];
        int li = v2 & 127;
        int p = eoff + excl[li] + atomicAdd(&cnt2[li], 1);
        col[p] = v2 >> 7;          // 6.4KB window per bucket -> full line reuse
    }
}

// ---------------- fused: CSR walk (agg xs, dsum) + layer-1 1->16 linear+GELU+prescale ----------------
__global__ __launch_bounds__(256) void k_g1l1(const float2* __restrict__ xd,
                                              const int* __restrict__ rp, const int* __restrict__ col,
                                              const float* __restrict__ W, const float* __restrict__ bias,
                                              float* __restrict__ dsum, float* __restrict__ hs, int n){
    int node = blockIdx.x * 256 + threadIdx.x;
    if (node >= n) return;
    int beg = rp[node], end = rp[node + 1];
    float a0 = 0.f, a1 = 0.f, d0 = 0.f, d1 = 0.f;
    int j = beg;
    for (; j + 1 < end; j += 2){
        float2 v0 = xd[col[j]];
        float2 v1 = xd[col[j + 1]];
        a0 += v0.x; d0 += v0.y;
        a1 += v1.x; d1 += v1.y;
    }
    if (j < end){ float2 v0 = xd[col[j]]; a0 += v0.x; d0 += v0.y; }
    float2 self = xd[node];
    float dn = self.y;
    dsum[node] = d0 + d1 + dn;
    float a = dn * (a0 + a1 + self.x);
    float4* o = (float4*)(hs + (size_t)node * 16);
#pragma unroll
    for (int u = 0; u < 4; u++){
        float4 r;
        r.x = gelu_f(bias[u*4+0] + a * W[u*4+0]) * dn;
        r.y = gelu_f(bias[u*4+1] + a * W[u*4+1]) * dn;
        r.z = gelu_f(bias[u*4+2] + a * W[u*4+2]) * dn;
        r.w = gelu_f(bias[u*4+3] + a * W[u*4+3]) * dn;
        o[u] = r;
    }
}

// ---------------- gather of pre-scaled hs with inline BN affine (float4, 8-edge unroll) ----------------
template<int C>
__global__ __launch_bounds__(256) void k_gather(const float* __restrict__ hs, const int* __restrict__ rp,
                                                const int* __restrict__ col, const float* __restrict__ dis,
                                                const float* __restrict__ dsum, const float* __restrict__ stat,
                                                const float* __restrict__ gamma, const float* __restrict__ beta,
                                                float* __restrict__ outp, int n){
    constexpr int TPN = C / 4;
    int i = blockIdx.x * 256 + threadIdx.x;
    int node = i / TPN, q = i % TPN;
    if (node >= n) return;
    int c0 = q * 4;
    const float invn = 1.0f / (float)NN;
    float scv[4], shv[4];
#pragma unroll
    for (int u = 0; u < 4; u++){
        float mean = stat[c0 + u] * invn;
        float var  = stat[128 + c0 + u] * invn - mean * mean;
        float sc   = gamma[c0 + u] * rsqrtf(var + 1e-5f);
        scv[u] = sc;
        shv[u] = beta[c0 + u] - mean * sc;
    }
    const float4* h4 = (const float4*)hs;
    int beg = rp[node], end = rp[node + 1];
    float a0 = 0.f, a1 = 0.f, a2 = 0.f, a3 = 0.f;
    float b0 = 0.f, b1 = 0.f, b2 = 0.f, b3 = 0.f;
    int j = beg;
    for (; j + 7 < end; j += 8){
        int i0 = col[j],   i1 = col[j+1], i2 = col[j+2], i3 = col[j+3];
        int i4 = col[j+4], i5 = col[j+5], i6 = col[j+6], i7 = col[j+7];
        float4 v0 = h4[i0 * TPN + q];
        float4 v1 = h4[i1 * TPN + q];
        float4 v2 = h4[i2 * TPN + q];
        float4 v3 = h4[i3 * TPN + q];
        float4 v4 = h4[i4 * TPN + q];
        float4 v5 = h4[i5 * TPN + q];
        float4 v6 = h4[i6 * TPN + q];
        float4 v7 = h4[i7 * TPN + q];
        a0 += v0.x; a1 += v0.y; a2 += v0.z; a3 += v0.w;
        b0 += v1.x; b1 += v1.y; b2 += v1.z; b3 += v1.w;
        a0 += v2.x; a1 += v2.y; a2 += v2.z; a3 += v2.w;
        b0 += v3.x; b1 += v3.y; b2 += v3.z; b3 += v3.w;
        a0 += v4.x; a1 += v4.y; a2 += v4.z; a3 += v4.w;
        b0 += v5.x; b1 += v5.y; b2 += v5.z; b3 += v5.w;
        a0 += v6.x; a1 += v6.y; a2 += v6.z; a3 += v6.w;
        b0 += v7.x; b1 += v7.y; b2 += v7.z; b3 += v7.w;
    }
    for (; j < end; j++){
        float4 v = h4[col[j] * TPN + q];
        a0 += v.x; a1 += v.y; a2 += v.z; a3 += v.w;
    }
    float4 vs = h4[node * TPN + q];    // self loop (weight 1 in pre-scaled space)
    a0 += vs.x; a1 += vs.y; a2 += vs.z; a3 += vs.w;
    a0 += b0; a1 += b1; a2 += b2; a3 += b3;
    float dn = dis[node];
    float dsm = dsum[node];
    float4 r = make_float4((a0 * scv[0] + shv[0] * dsm) * dn,
                           (a1 * scv[1] + shv[1] * dsm) * dn,
                           (a2 * scv[2] + shv[2] * dsm) * dn,
                           (a3 * scv[3] + shv[3] * dsm) * dn);
    ((float4*)outp)[node * TPN + q] = r;
}

// ---------------- dense linear + bias + GELU: 4 nodes x 4 channels per thread ----------------
template<int CIN, int COUT, bool SCALE>
__global__ __launch_bounds__(256) void k_linT(const float* __restrict__ xin, const float* __restrict__ dis,
                                              const float* __restrict__ W,
                                              const float* __restrict__ bias, float* __restrict__ outp, int n){
    constexpr int QC = COUT / 4;
    constexpr int K4 = CIN / 4;
    int i = blockIdx.x * 256 + threadIdx.x;
    int tile = i / QC, q = i % QC;
    int n0 = tile * 4;                 // NN % 4 == 0
    if (n0 >= n) return;
    const float4* xp0 = (const float4*)(xin + (size_t)(n0 + 0) * CIN);
    const float4* xp1 = (const float4*)(xin + (size_t)(n0 + 1) * CIN);
    const float4* xp2 = (const float4*)(xin + (size_t)(n0 + 2) * CIN);
    const float4* xp3 = (const float4*)(xin + (size_t)(n0 + 3) * CIN);
    const float4* Wq = (const float4*)W + q;      // row k at Wq[k * QC]
    float4 bb = ((const float4*)bias)[q];
    float acc[4][4];
#pragma unroll
    for (int nd = 0; nd < 4; nd++){
        acc[nd][0] = bb.x; acc[nd][1] = bb.y; acc[nd][2] = bb.z; acc[nd][3] = bb.w;
    }
#pragma unroll 1
    for (int k4 = 0; k4 < K4; k4++){
        float4 xv[4];
        xv[0] = xp0[k4]; xv[1] = xp1[k4]; xv[2] = xp2[k4]; xv[3] = xp3[k4];
        float4 w0 = Wq[(k4 * 4 + 0) * QC];
        float4 w1 = Wq[(k4 * 4 + 1) * QC];
        float4 w2 = Wq[(k4 * 4 + 2) * QC];
        float4 w3 = Wq[(k4 * 4 + 3) * QC];
#pragma unroll
        for (int nd = 0; nd < 4; nd++){
            acc[nd][0] += xv[nd].x*w0.x + xv[nd].y*w1.x + xv[nd].z*w2.x + xv[nd].w*w3.x;
            acc[nd][1] += xv[nd].x*w0.y + xv[nd].y*w1.y + xv[nd].z*w2.y + xv[nd].w*w3.y;
            acc[nd][2] += xv[nd].x*w0.z + xv[nd].y*w1.z + xv[nd].z*w2.z + xv[nd].w*w3.z;
            acc[nd][3] += xv[nd].x*w0.w + xv[nd].y*w1.w + xv[nd].z*w2.w + xv[nd].w*w3.w;
        }
    }
    float4* o4 = (float4*)outp;
#pragma unroll
    for (int nd = 0; nd < 4; nd++){
        float sc = SCALE ? dis[n0 + nd] : 1.0f;
        o4[(size_t)(n0 + nd) * QC + q] =
            make_float4(gelu_f(acc[nd][0])*sc, gelu_f(acc[nd][1])*sc,
                        gelu_f(acc[nd][2])*sc, gelu_f(acc[nd][3])*sc);
    }
}

// ---------------- BN stats over raw h (de-scale pre-scaled hs by invdis) ----------------
template<int C>
__global__ __launch_bounds__(256) void k_stats(const float* __restrict__ hs, const float* __restrict__ invdis,
                                               float* __restrict__ stat, int n){
    constexpr int REP = 256 / C;
    int t = threadIdx.x;
    int rep = t / C;
    int c = t % C;
    float s = 0.f, q = 0.f;
    for (int row = blockIdx.x * REP + rep; row < n; row += gridDim.x * REP){
        float v = hs[(long long)row * C + c] * invdis[row];
        s += v; q += v * v;
    }
    __shared__ float ss[256], sq[256];
    ss[t] = s; sq[t] = q;
    __syncthreads();
    for (int off = 128; off >= C; off >>= 1){
        if (t < off){ ss[t] += ss[t + off]; sq[t] += sq[t + off]; }
        __syncthreads();
    }
    if (t < C){
        atomicAdd(&stat[t], ss[t]);
        atomicAdd(&stat[128 + t], sq[t]);
    }
}

// ---------------- mean-pool: one block per graph, binary search sorted batch, no atomics ----------------
__global__ __launch_bounds__(128) void k_pool(const float* __restrict__ h4, const int* __restrict__ batch,
                                              float* __restrict__ pool, int n){
    int g = blockIdx.x;
    int t = threadIdx.x;
    int lo = 0, hi = n;
    while (lo < hi){ int mid = (lo + hi) >> 1; if (batch[mid] < g) lo = mid + 1; else hi = mid; }
    int s = lo;
    hi = n;
    while (lo < hi){ int mid = (lo + hi) >> 1; if (batch[mid] < g + 1) lo = mid + 1; else hi = mid; }
    int e = lo;
    float a0 = 0.f, a1 = 0.f, a2 = 0.f, a3 = 0.f;
    int node = s;
    for (; node + 3 < e; node += 4){
        a0 += h4[(size_t)(node + 0) * 128 + t];
        a1 += h4[(size_t)(node + 1) * 128 + t];
        a2 += h4[(size_t)(node + 2) * 128 + t];
        a3 += h4[(size_t)(node + 3) * 128 + t];
    }
    for (; node < e; node++) a0 += h4[(size_t)node * 128 + t];
    float sum = (a0 + a1) + (a2 + a3);
    pool[g * 128 + t] = sum / fmaxf((float)(e - s), 1.0f);
}

// ---------------- MLP head: 256 graphs, one block each ----------------
__global__ __launch_bounds__(128) void k_mlp(const float* __restrict__ pool,
                                             const float* __restrict__ yex,
                                             const float* __restrict__ lw1, const float* __restrict__ lb1,
                                             const float* __restrict__ lw2, const float* __restrict__ lb2,
                                             const float* __restrict__ lw3, const float* __restrict__ lb3,
                                             const float* __restrict__ lw4, const float* __restrict__ lb4,
                                             float* __restrict__ outp){
    int g = blockIdx.x;
    int t = threadIdx.x;
    __shared__ float z[136];
    __shared__ float z2[128];
    __shared__ float z3[64];
    __shared__ float z4[32];
    z[t] = pool[g * 128 + t];
    if (t < 7) z[128 + t] = yex[g * 7 + t];
    __syncthreads();
    {   // 135 -> 128
        float acc = lb1[t];
        for (int k = 0; k < 135; k++) acc += z[k] * lw1[k * 128 + t];
        z2[t] = gelu_f(acc);
    }
    __syncthreads();
    if (t < 64){   // 128 -> 64
        float acc = lb2[t];
        for (int k = 0; k < 128; k++) acc += z2[k] * lw2[k * 64 + t];
        z3[t] = gelu_f(acc);
    }
    __syncthreads();
    if (t < 32){   // 64 -> 32
        float acc = lb3[t];
        for (int k = 0; k < 64; k++) acc += z3[k] * lw3[k * 32 + t];
        z4[t] = gelu_f(acc);
    }
    __syncthreads();
    if (t < 2){    // 32 -> 2, sigmoid
        float acc = lb4[t];
        for (int k = 0; k < 32; k++) acc += z4[k] * lw4[k * 2 + t];
        outp[g * 2 + t] = 1.0f / (1.0f + expf(-acc));
    }
}

extern "C" void kernel_launch(void* const* d_in, const int* in_sizes, int n_in,
                              void* d_out, int out_size, void* d_ws, size_t ws_size,
                              hipStream_t stream) {
    const float* x     = (const float*)d_in[0];
    const int*   ei    = (const int*)  d_in[1];   // [2, E]: src = ei, dst = ei+E
    const int*   batch = (const int*)  d_in[2];
    const float* yex   = (const float*)d_in[3];
    const float* W1 = (const float*)d_in[4];  const float* b1 = (const float*)d_in[5];
    const float* W2 = (const float*)d_in[6];  const float* b2 = (const float*)d_in[7];
    const float* W3 = (const float*)d_in[8];  const float* b3 = (const float*)d_in[9];
    const float* W4 = (const float*)d_in[10]; const float* b4 = (const float*)d_in[11];
    const float* g1 = (const float*)d_in[12]; const float* be1 = (const float*)d_in[13];
    const float* g2 = (const float*)d_in[14]; const float* be2 = (const float*)d_in[15];
    const float* g3 = (const float*)d_in[16]; const float* be3 = (const float*)d_in[17];
    const float* lw1 = (const float*)d_in[18]; const float* lb1 = (const float*)d_in[19];
    const float* lw2 = (const float*)d_in[20]; const float* lb2 = (const float*)d_in[21];
    const float* lw3 = (const float*)d_in[22]; const float* lb3 = (const float*)d_in[23];
    const float* lw4 = (const float*)d_in[24]; const float* lb4 = (const float*)d_in[25];
    float* out = (float*)d_out;

    // ---- workspace carve (256B-aligned); zero-region first ----
    char* wsb = (char*)d_ws;
    size_t off = 0;
    auto alloc = [&](size_t elems) -> void* {
        void* p = wsb + off;
        off += ((elems * 4 + 255) / 256) * 256;
        return p;
    };
    float* stats        = (float*)alloc(3 * 256);      // layer l: [l*256+c]=sum, [+128]=sumsq
    int*   bucket_cnt_p = (int*)  alloc(NBUCK * 16);   // padded: 1 line per bucket
    size_t zero_bytes = off;
    int*   bucket_off   = (int*)  alloc(NBUCK);
    int*   cursor_p     = (int*)  alloc(NBUCK * 16);
    int*   ebuf         = (int*)  alloc(EE);           // packed (src<<7 | dst%NPB)
    float* pool   = (float*)alloc(GG * 128);
    int*   rp     = (int*)  alloc(NN + 1);
    float* dis    = (float*)alloc(NN);
    float* invdis = (float*)alloc(NN);
    float* dsum   = (float*)alloc(NN);
    float2* xd    = (float2*)alloc(NN * 2);            // (xs, dis) packed
    int*   col    = (int*)  alloc(EE);
    float* hbuf   = (float*)alloc((size_t)NN * 128);  // hs (16/32/64 ch) and raw h4 (128 ch)
    float* abuf   = (float*)alloc((size_t)NN * 64);   // aggregated conv inputs (<=64 ch)

    hipMemsetAsync(d_ws, 0, zero_bytes, stream);

    auto nb = [](long long total){ return (int)((total + 255) / 256); };

    // ---- CSR build via LDS-binned radix partition (no global random scatter) ----
    k_hist   <<<NEB, 256, 0, stream>>>(ei + EE, bucket_cnt_p, EE);
    k_bscan  <<<1, 512, 0, stream>>>(bucket_cnt_p, bucket_off, cursor_p);
    k_scatter<<<NEB, 256, 0, stream>>>(ei, ei + EE, cursor_p, ebuf, EE);
    k_build  <<<NBUCK, 256, 0, stream>>>(ebuf, bucket_cnt_p, bucket_off, rp, col, dis, invdis, xd, x, NN);

    // ---- layer 1: fused CSR-walk (agg xs + dsum) + 1->16 linear+gelu (pre-scaled), stats ----
    k_g1l1<<<NB_NODE, 256, 0, stream>>>(xd, rp, col, W1, b1, dsum, hbuf, NN);
    k_stats<16><<<128, 256, 0, stream>>>(hbuf, invdis, stats + 0, NN);

    // ---- layer 2: gather hs1 (BN1 inline), 16->32 linear+gelu (pre-scaled), stats ----
    k_gather<16><<<nb((long long)NN * 4), 256, 0, stream>>>(hbuf, rp, col, dis, dsum, stats + 0, g1, be1, abuf, NN);
    k_linT<16, 32, true><<<nb((long long)(NN / 4) * 8), 256, 0, stream>>>(abuf, dis, W2, b2, hbuf, NN);
    k_stats<32><<<128, 256, 0, stream>>>(hbuf, invdis, stats + 256, NN);

    // ---- layer 3: gather hs2 (BN2 inline), 32->64 linear+gelu (pre-scaled), stats ----
    k_gather<32><<<nb((long long)NN * 8), 256, 0, stream>>>(hbuf, rp, col, dis, dsum, stats + 256, g2, be2, abuf, NN);
    k_linT<32, 64, true><<<nb((long long)(NN / 4) * 16), 256, 0, stream>>>(abuf, dis, W3, b3, hbuf, NN);
    k_stats<64><<<128, 256, 0, stream>>>(hbuf, invdis, stats + 512, NN);

    // ---- layer 4: gather hs3 (BN3 inline), 64->128 linear+gelu (raw out), streaming mean pool ----
    k_gather<64><<<nb((long long)NN * 16), 256, 0, stream>>>(hbuf, rp, col, dis, dsum, stats + 512, g3, be3, abuf, NN);
    k_linT<64, 128, false><<<nb((long long)(NN / 4) * 32), 256, 0, stream>>>(abuf, dis, W4, b4, hbuf, NN);
    k_pool<<<GG, 128, 0, stream>>>(hbuf, batch, pool, NN);

    // ---- MLP head ----
    k_mlp<<<GG, 128, 0, stream>>>(pool, yex,
                                  lw1, lb1, lw2, lb2, lw3, lb3, lw4, lb4, out);
}

// Round 14
// 356.460 us; speedup vs baseline: 1.2140x; 1.0184x over previous
//
#include <hip/hip_runtime.h>
#include <math.h>

#define NN 50000
#define EE 800000
#define GG 256
#define NPB 100          // nodes per bucket (<128 so local idx fits in 7 bits)
#define NBUCK 500        // NN / NPB exactly
#define EPB 4096         // edges per block chunk (hist/scatter)
#define NEB 196          // ceil(EE/EPB)
#define NB_NODE 196      // ceil(NN/256) node-parallel grids

__device__ __forceinline__ float gelu_f(float v){
    return 0.5f * v * (1.0f + erff(v * 0.70710678118654752f));
}

// ---------------- bucket histogram of dst (LDS-privatized, padded global) ----------------
__global__ __launch_bounds__(256) void k_hist(const int* __restrict__ dst, int* __restrict__ bucket_cnt_p, int e){
    __shared__ int hist[512];
    int t = threadIdx.x;
    int start = blockIdx.x * EPB;
    for (int k = t; k < 512; k += 256) hist[k] = 0;
    __syncthreads();
#pragma unroll
    for (int k = 0; k < EPB / 256; k++){
        int idx = start + k * 256 + t;
        if (idx < e) atomicAdd(&hist[dst[idx] / NPB], 1);
    }
    __syncthreads();
    for (int k = t; k < NBUCK; k += 256){
        int h = hist[k];
        if (h) atomicAdd(&bucket_cnt_p[k * 16], h);   // *16: one cache line per bucket
    }
}

// ---------------- scan bucket counts -> offsets + scatter cursors ----------------
__global__ __launch_bounds__(512) void k_bscan(const int* __restrict__ bucket_cnt_p,
                                               int* __restrict__ bucket_off, int* __restrict__ cursor_p){
    __shared__ int s[512];
    int t = threadIdx.x;
    int v = (t < NBUCK) ? bucket_cnt_p[t * 16] : 0;
    s[t] = v;
    __syncthreads();
    for (int off = 1; off < 512; off <<= 1){
        int u = (t >= off) ? s[t - off] : 0;
        __syncthreads();
        s[t] += u;
        __syncthreads();
    }
    if (t < NBUCK){
        int ex = s[t] - v;
        bucket_off[t] = ex;
        cursor_p[t * 16] = ex;
    }
}

// ---------------- partition packed (src<<7 | dst%NPB) into bucket-contiguous ebuf ----------------
__global__ __launch_bounds__(256) void k_scatter(const int* __restrict__ src, const int* __restrict__ dst,
                                                 int* __restrict__ cursor_p, int* __restrict__ ebuf, int e){
    __shared__ int hist[512], base[512];
    int t = threadIdx.x;
    int start = blockIdx.x * EPB;
    for (int k = t; k < 512; k += 256) hist[k] = 0;
    __syncthreads();
    int pk[EPB / 256], bb[EPB / 256];
    int cntl = 0;
#pragma unroll
    for (int k = 0; k < EPB / 256; k++){
        int idx = start + k * 256 + t;
        if (idx < e){
            int s_ = src[idx], d_ = dst[idx];
            int b_ = d_ / NPB;
            pk[cntl] = (s_ << 7) | (d_ - b_ * NPB);
            bb[cntl] = b_;
            atomicAdd(&hist[b_], 1);
            cntl++;
        }
    }
    __syncthreads();
    for (int k = t; k < NBUCK; k += 256){
        int h = hist[k];
        base[k] = h ? atomicAdd(&cursor_p[k * 16], h) : 0;
    }
    __syncthreads();
    for (int k = t; k < 512; k += 256) hist[k] = 0;
    __syncthreads();
    for (int k = 0; k < cntl; k++){
        int b_ = bb[k];
        int pos = base[b_] + atomicAdd(&hist[b_], 1);
        ebuf[pos] = pk[k];
    }
}

// ---------------- per-bucket CSR finalize: rp/col + dis/invdis/xd (LDS only) ----------------
__global__ __launch_bounds__(256) void k_build(const int* __restrict__ ebuf,
                                               const int* __restrict__ bucket_cnt_p,
                                               const int* __restrict__ bucket_off,
                                               int* __restrict__ rp, int* __restrict__ col,
                                               float* __restrict__ dis, float* __restrict__ invdis,
                                               float2* __restrict__ xd,
                                               const float* __restrict__ x, int n){
    int b = blockIdx.x;
    int t = threadIdx.x;
    int nbase = b * NPB;
    int eoff = bucket_off[b];
    int ecnt = bucket_cnt_p[b * 16];
    __shared__ int cnt[128], excl[128], cnt2[128], s[128];
    if (t < 128){ cnt[t] = 0; cnt2[t] = 0; }
    __syncthreads();
    for (int j = t; j < ecnt; j += 256)
        atomicAdd(&cnt[ebuf[eoff + j] & 127], 1);
    __syncthreads();
    int v = (t < 128) ? cnt[t] : 0;
    if (t < 128) s[t] = v;
    __syncthreads();
    for (int off = 1; off < 128; off <<= 1){
        int u = (t < 128 && t >= off) ? s[t - off] : 0;
        __syncthreads();
        if (t < 128) s[t] += u;
        __syncthreads();
    }
    if (t < 128) excl[t] = s[t] - v;
    __syncthreads();
    if (t < NPB){
        int node = nbase + t;      // NBUCK*NPB == NN exactly
        int dgg = cnt[t];
        rp[node] = eoff + excl[t];
        float dv = rsqrtf((float)(dgg + 1));   // +1 self loop
        dis[node] = dv;
        invdis[node] = sqrtf((float)(dgg + 1));
        xd[node] = make_float2(dv * x[node], dv);   // (xs, dis) packed
    }
    if (b == NBUCK - 1 && t == 0) rp[n] = eoff + ecnt;   // == E
    __syncthreads();
    for (int j = t; j < ecnt; j += 256){
        int v2 = ebuf[eoff + j];
        int li = v2 & 127;
        int p = eoff + excl[li] + atomicAdd(&cnt2[li], 1);
        col[p] = v2 >> 7;          // 6.4KB window per bucket -> full line reuse
    }
}

// ---------------- fused: CSR walk (agg xs, dsum) + layer-1 1->16 linear+GELU+prescale ----------------
__global__ __launch_bounds__(256) void k_g1l1(const float2* __restrict__ xd,
                                              const int* __restrict__ rp, const int* __restrict__ col,
                                              const float* __restrict__ W, const float* __restrict__ bias,
                                              float* __restrict__ dsum, float* __restrict__ hs, int n){
    int node = blockIdx.x * 256 + threadIdx.x;
    if (node >= n) return;
    int beg = rp[node], end = rp[node + 1];
    float a0 = 0.f, a1 = 0.f, d0 = 0.f, d1 = 0.f;
    int j = beg;
    for (; j + 1 < end; j += 2){
        float2 v0 = xd[col[j]];
        float2 v1 = xd[col[j + 1]];
        a0 += v0.x; d0 += v0.y;
        a1 += v1.x; d1 += v1.y;
    }
    if (j < end){ float2 v0 = xd[col[j]]; a0 += v0.x; d0 += v0.y; }
    float2 self = xd[node];
    float dn = self.y;
    dsum[node] = d0 + d1 + dn;
    float a = dn * (a0 + a1 + self.x);
    float4* o = (float4*)(hs + (size_t)node * 16);
#pragma unroll
    for (int u = 0; u < 4; u++){
        float4 r;
        r.x = gelu_f(bias[u*4+0] + a * W[u*4+0]) * dn;
        r.y = gelu_f(bias[u*4+1] + a * W[u*4+1]) * dn;
        r.z = gelu_f(bias[u*4+2] + a * W[u*4+2]) * dn;
        r.w = gelu_f(bias[u*4+3] + a * W[u*4+3]) * dn;
        o[u] = r;
    }
}

// ---------------- gather of pre-scaled hs with inline BN affine (float4, 8-edge unroll) ----------------
template<int C>
__global__ __launch_bounds__(256) void k_gather(const float* __restrict__ hs, const int* __restrict__ rp,
                                                const int* __restrict__ col, const float* __restrict__ dis,
                                                const float* __restrict__ dsum, const float* __restrict__ stat,
                                                const float* __restrict__ gamma, const float* __restrict__ beta,
                                                float* __restrict__ outp, int n){
    constexpr int TPN = C / 4;
    int i = blockIdx.x * 256 + threadIdx.x;
    int node = i / TPN, q = i % TPN;
    if (node >= n) return;
    int c0 = q * 4;
    const float invn = 1.0f / (float)NN;
    float scv[4], shv[4];
#pragma unroll
    for (int u = 0; u < 4; u++){
        float mean = stat[c0 + u] * invn;
        float var  = stat[128 + c0 + u] * invn - mean * mean;
        float sc   = gamma[c0 + u] * rsqrtf(var + 1e-5f);
        scv[u] = sc;
        shv[u] = beta[c0 + u] - mean * sc;
    }
    const float4* h4 = (const float4*)hs;
    int beg = rp[node], end = rp[node + 1];
    float a0 = 0.f, a1 = 0.f, a2 = 0.f, a3 = 0.f;
    float b0 = 0.f, b1 = 0.f, b2 = 0.f, b3 = 0.f;
    int j = beg;
    for (; j + 7 < end; j += 8){
        int i0 = col[j],   i1 = col[j+1], i2 = col[j+2], i3 = col[j+3];
        int i4 = col[j+4], i5 = col[j+5], i6 = col[j+6], i7 = col[j+7];
        float4 v0 = h4[i0 * TPN + q];
        float4 v1 = h4[i1 * TPN + q];
        float4 v2 = h4[i2 * TPN + q];
        float4 v3 = h4[i3 * TPN + q];
        float4 v4 = h4[i4 * TPN + q];
        float4 v5 = h4[i5 * TPN + q];
        float4 v6 = h4[i6 * TPN + q];
        float4 v7 = h4[i7 * TPN + q];
        a0 += v0.x; a1 += v0.y; a2 += v0.z; a3 += v0.w;
        b0 += v1.x; b1 += v1.y; b2 += v1.z; b3 += v1.w;
        a0 += v2.x; a1 += v2.y; a2 += v2.z; a3 += v2.w;
        b0 += v3.x; b1 += v3.y; b2 += v3.z; b3 += v3.w;
        a0 += v4.x; a1 += v4.y; a2 += v4.z; a3 += v4.w;
        b0 += v5.x; b1 += v5.y; b2 += v5.z; b3 += v5.w;
        a0 += v6.x; a1 += v6.y; a2 += v6.z; a3 += v6.w;
        b0 += v7.x; b1 += v7.y; b2 += v7.z; b3 += v7.w;
    }
    for (; j < end; j++){
        float4 v = h4[col[j] * TPN + q];
        a0 += v.x; a1 += v.y; a2 += v.z; a3 += v.w;
    }
    float4 vs = h4[node * TPN + q];    // self loop (weight 1 in pre-scaled space)
    a0 += vs.x; a1 += vs.y; a2 += vs.z; a3 += vs.w;
    a0 += b0; a1 += b1; a2 += b2; a3 += b3;
    float dn = dis[node];
    float dsm = dsum[node];
    float4 r = make_float4((a0 * scv[0] + shv[0] * dsm) * dn,
                           (a1 * scv[1] + shv[1] * dsm) * dn,
                           (a2 * scv[2] + shv[2] * dsm) * dn,
                           (a3 * scv[3] + shv[3] * dsm) * dn);
    ((float4*)outp)[node * TPN + q] = r;
}

// ---------------- dense linear + bias + GELU: 4 nodes x 4 channels per thread, W staged in LDS ----------------
// Round-13 post-mortem: k_linT<64,128> pinned at ~44us, VALUBusy 21% -> W re-loads from
// vector cache dominate issue slots. Stage W once per block in LDS (2/8/32 KB); K-loop
// then reads W at LDS throughput while 4 x-row float4 loads stream through L1.
template<int CIN, int COUT, bool SCALE>
__global__ __launch_bounds__(256) void k_linT(const float* __restrict__ xin, const float* __restrict__ dis,
                                              const float* __restrict__ W,
                                              const float* __restrict__ bias, float* __restrict__ outp, int n){
    constexpr int QC = COUT / 4;
    constexpr int K4 = CIN / 4;
    __shared__ float4 Wl[CIN * QC];           // Wl[k * QC + q] = W[k][4q..4q+3]
    for (int idx = threadIdx.x; idx < CIN * QC; idx += 256)
        Wl[idx] = ((const float4*)W)[idx];
    __syncthreads();
    int i = blockIdx.x * 256 + threadIdx.x;
    int tile = i / QC, q = i % QC;
    int n0 = tile * 4;                 // NN % 4 == 0
    if (n0 >= n) return;
    const float4* xp0 = (const float4*)(xin + (size_t)(n0 + 0) * CIN);
    const float4* xp1 = (const float4*)(xin + (size_t)(n0 + 1) * CIN);
    const float4* xp2 = (const float4*)(xin + (size_t)(n0 + 2) * CIN);
    const float4* xp3 = (const float4*)(xin + (size_t)(n0 + 3) * CIN);
    float4 bb = ((const float4*)bias)[q];
    float acc[4][4];
#pragma unroll
    for (int nd = 0; nd < 4; nd++){
        acc[nd][0] = bb.x; acc[nd][1] = bb.y; acc[nd][2] = bb.z; acc[nd][3] = bb.w;
    }
#pragma unroll 1
    for (int k4 = 0; k4 < K4; k4++){
        float4 xv[4];
        xv[0] = xp0[k4]; xv[1] = xp1[k4]; xv[2] = xp2[k4]; xv[3] = xp3[k4];
        float4 w0 = Wl[(k4 * 4 + 0) * QC + q];
        float4 w1 = Wl[(k4 * 4 + 1) * QC + q];
        float4 w2 = Wl[(k4 * 4 + 2) * QC + q];
        float4 w3 = Wl[(k4 * 4 + 3) * QC + q];
#pragma unroll
        for (int nd = 0; nd < 4; nd++){
            acc[nd][0] += xv[nd].x*w0.x + xv[nd].y*w1.x + xv[nd].z*w2.x + xv[nd].w*w3.x;
            acc[nd][1] += xv[nd].x*w0.y + xv[nd].y*w1.y + xv[nd].z*w2.y + xv[nd].w*w3.y;
            acc[nd][2] += xv[nd].x*w0.z + xv[nd].y*w1.z + xv[nd].z*w2.z + xv[nd].w*w3.z;
            acc[nd][3] += xv[nd].x*w0.w + xv[nd].y*w1.w + xv[nd].z*w2.w + xv[nd].w*w3.w;
        }
    }
    float4* o4 = (float4*)outp;
#pragma unroll
    for (int nd = 0; nd < 4; nd++){
        float sc = SCALE ? dis[n0 + nd] : 1.0f;
        o4[(size_t)(n0 + nd) * QC + q] =
            make_float4(gelu_f(acc[nd][0])*sc, gelu_f(acc[nd][1])*sc,
                        gelu_f(acc[nd][2])*sc, gelu_f(acc[nd][3])*sc);
    }
}

// ---------------- BN stats over raw h (de-scale pre-scaled hs by invdis) ----------------
template<int C>
__global__ __launch_bounds__(256) void k_stats(const float* __restrict__ hs, const float* __restrict__ invdis,
                                               float* __restrict__ stat, int n){
    constexpr int REP = 256 / C;
    int t = threadIdx.x;
    int rep = t / C;
    int c = t % C;
    float s = 0.f, q = 0.f;
    for (int row = blockIdx.x * REP + rep; row < n; row += gridDim.x * REP){
        float v = hs[(long long)row * C + c] * invdis[row];
        s += v; q += v * v;
    }
    __shared__ float ss[256], sq[256];
    ss[t] = s; sq[t] = q;
    __syncthreads();
    for (int off = 128; off >= C; off >>= 1){
        if (t < off){ ss[t] += ss[t + off]; sq[t] += sq[t + off]; }
        __syncthreads();
    }
    if (t < C){
        atomicAdd(&stat[t], ss[t]);
        atomicAdd(&stat[128 + t], sq[t]);
    }
}

// ---------------- mean-pool: one block per graph, binary search sorted batch, no atomics ----------------
__global__ __launch_bounds__(128) void k_pool(const float* __restrict__ h4, const int* __restrict__ batch,
                                              float* __restrict__ pool, int n){
    int g = blockIdx.x;
    int t = threadIdx.x;
    int lo = 0, hi = n;
    while (lo < hi){ int mid = (lo + hi) >> 1; if (batch[mid] < g) lo = mid + 1; else hi = mid; }
    int s = lo;
    hi = n;
    while (lo < hi){ int mid = (lo + hi) >> 1; if (batch[mid] < g + 1) lo = mid + 1; else hi = mid; }
    int e = lo;
    float a0 = 0.f, a1 = 0.f, a2 = 0.f, a3 = 0.f;
    int node = s;
    for (; node + 3 < e; node += 4){
        a0 += h4[(size_t)(node + 0) * 128 + t];
        a1 += h4[(size_t)(node + 1) * 128 + t];
        a2 += h4[(size_t)(node + 2) * 128 + t];
        a3 += h4[(size_t)(node + 3) * 128 + t];
    }
    for (; node < e; node++) a0 += h4[(size_t)node * 128 + t];
    float sum = (a0 + a1) + (a2 + a3);
    pool[g * 128 + t] = sum / fmaxf((float)(e - s), 1.0f);
}

// ---------------- MLP head: 256 graphs, one block each ----------------
__global__ __launch_bounds__(128) void k_mlp(const float* __restrict__ pool,
                                             const float* __restrict__ yex,
                                             const float* __restrict__ lw1, const float* __restrict__ lb1,
                                             const float* __restrict__ lw2, const float* __restrict__ lb2,
                                             const float* __restrict__ lw3, const float* __restrict__ lb3,
                                             const float* __restrict__ lw4, const float* __restrict__ lb4,
                                             float* __restrict__ outp){
    int g = blockIdx.x;
    int t = threadIdx.x;
    __shared__ float z[136];
    __shared__ float z2[128];
    __shared__ float z3[64];
    __shared__ float z4[32];
    z[t] = pool[g * 128 + t];
    if (t < 7) z[128 + t] = yex[g * 7 + t];
    __syncthreads();
    {   // 135 -> 128
        float acc = lb1[t];
        for (int k = 0; k < 135; k++) acc += z[k] * lw1[k * 128 + t];
        z2[t] = gelu_f(acc);
    }
    __syncthreads();
    if (t < 64){   // 128 -> 64
        float acc = lb2[t];
        for (int k = 0; k < 128; k++) acc += z2[k] * lw2[k * 64 + t];
        z3[t] = gelu_f(acc);
    }
    __syncthreads();
    if (t < 32){   // 64 -> 32
        float acc = lb3[t];
        for (int k = 0; k < 64; k++) acc += z3[k] * lw3[k * 32 + t];
        z4[t] = gelu_f(acc);
    }
    __syncthreads();
    if (t < 2){    // 32 -> 2, sigmoid
        float acc = lb4[t];
        for (int k = 0; k < 32; k++) acc += z4[k] * lw4[k * 2 + t];
        outp[g * 2 + t] = 1.0f / (1.0f + expf(-acc));
    }
}

extern "C" void kernel_launch(void* const* d_in, const int* in_sizes, int n_in,
                              void* d_out, int out_size, void* d_ws, size_t ws_size,
                              hipStream_t stream) {
    const float* x     = (const float*)d_in[0];
    const int*   ei    = (const int*)  d_in[1];   // [2, E]: src = ei, dst = ei+E
    const int*   batch = (const int*)  d_in[2];
    const float* yex   = (const float*)d_in[3];
    const float* W1 = (const float*)d_in[4];  const float* b1 = (const float*)d_in[5];
    const float* W2 = (const float*)d_in[6];  const float* b2 = (const float*)d_in[7];
    const float* W3 = (const float*)d_in[8];  const float* b3 = (const float*)d_in[9];
    const float* W4 = (const float*)d_in[10]; const float* b4 = (const float*)d_in[11];
    const float* g1 = (const float*)d_in[12]; const float* be1 = (const float*)d_in[13];
    const float* g2 = (const float*)d_in[14]; const float* be2 = (const float*)d_in[15];
    const float* g3 = (const float*)d_in[16]; const float* be3 = (const float*)d_in[17];
    const float* lw1 = (const float*)d_in[18]; const float* lb1 = (const float*)d_in[19];
    const float* lw2 = (const float*)d_in[20]; const float* lb2 = (const float*)d_in[21];
    const float* lw3 = (const float*)d_in[22]; const float* lb3 = (const float*)d_in[23];
    const float* lw4 = (const float*)d_in[24]; const float* lb4 = (const float*)d_in[25];
    float* out = (float*)d_out;

    // ---- workspace carve (256B-aligned); zero-region first ----
    char* wsb = (char*)d_ws;
    size_t off = 0;
    auto alloc = [&](size_t elems) -> void* {
        void* p = wsb + off;
        off += ((elems * 4 + 255) / 256) * 256;
        return p;
    };
    float* stats        = (float*)alloc(3 * 256);      // layer l: [l*256+c]=sum, [+128]=sumsq
    int*   bucket_cnt_p = (int*)  alloc(NBUCK * 16);   // padded: 1 line per bucket
    size_t zero_bytes = off;
    int*   bucket_off   = (int*)  alloc(NBUCK);
    int*   cursor_p     = (int*)  alloc(NBUCK * 16);
    int*   ebuf         = (int*)  alloc(EE);           // packed (src<<7 | dst%NPB)
    float* pool   = (float*)alloc(GG * 128);
    int*   rp     = (int*)  alloc(NN + 1);
    float* dis    = (float*)alloc(NN);
    float* invdis = (float*)alloc(NN);
    float* dsum   = (float*)alloc(NN);
    float2* xd    = (float2*)alloc(NN * 2);            // (xs, dis) packed
    int*   col    = (int*)  alloc(EE);
    float* hbuf   = (float*)alloc((size_t)NN * 128);  // hs (16/32/64 ch) and raw h4 (128 ch)
    float* abuf   = (float*)alloc((size_t)NN * 64);   // aggregated conv inputs (<=64 ch)

    hipMemsetAsync(d_ws, 0, zero_bytes, stream);

    auto nb = [](long long total){ return (int)((total + 255) / 256); };

    // ---- CSR build via LDS-binned radix partition (no global random scatter) ----
    k_hist   <<<NEB, 256, 0, stream>>>(ei + EE, bucket_cnt_p, EE);
    k_bscan  <<<1, 512, 0, stream>>>(bucket_cnt_p, bucket_off, cursor_p);
    k_scatter<<<NEB, 256, 0, stream>>>(ei, ei + EE, cursor_p, ebuf, EE);
    k_build  <<<NBUCK, 256, 0, stream>>>(ebuf, bucket_cnt_p, bucket_off, rp, col, dis, invdis, xd, x, NN);

    // ---- layer 1: fused CSR-walk (agg xs + dsum) + 1->16 linear+gelu (pre-scaled), stats ----
    k_g1l1<<<NB_NODE, 256, 0, stream>>>(xd, rp, col, W1, b1, dsum, hbuf, NN);
    k_stats<16><<<128, 256, 0, stream>>>(hbuf, invdis, stats + 0, NN);

    // ---- layer 2: gather hs1 (BN1 inline), 16->32 linear+gelu (pre-scaled), stats ----
    k_gather<16><<<nb((long long)NN * 4), 256, 0, stream>>>(hbuf, rp, col, dis, dsum, stats + 0, g1, be1, abuf, NN);
    k_linT<16, 32, true><<<nb((long long)(NN / 4) * 8), 256, 0, stream>>>(abuf, dis, W2, b2, hbuf, NN);
    k_stats<32><<<128, 256, 0, stream>>>(hbuf, invdis, stats + 256, NN);

    // ---- layer 3: gather hs2 (BN2 inline), 32->64 linear+gelu (pre-scaled), stats ----
    k_gather<32><<<nb((long long)NN * 8), 256, 0, stream>>>(hbuf, rp, col, dis, dsum, stats + 256, g2, be2, abuf, NN);
    k_linT<32, 64, true><<<nb((long long)(NN / 4) * 16), 256, 0, stream>>>(abuf, dis, W3, b3, hbuf, NN);
    k_stats<64><<<128, 256, 0, stream>>>(hbuf, invdis, stats + 512, NN);

    // ---- layer 4: gather hs3 (BN3 inline), 64->128 linear+gelu (raw out), streaming mean pool ----
    k_gather<64><<<nb((long long)NN * 16), 256, 0, stream>>>(hbuf, rp, col, dis, dsum, stats + 512, g3, be3, abuf, NN);
    k_linT<64, 128, false><<<nb((long long)(NN / 4) * 32), 256, 0, stream>>>(abuf, dis, W4, b4, hbuf, NN);
    k_pool<<<GG, 128, 0, stream>>>(hbuf, batch, pool, NN);

    // ---- MLP head ----
    k_mlp<<<GG, 128, 0, stream>>>(pool, yex,
                                  lw1, lb1, lw2, lb2, lw3, lb3, lw4, lb4, out);
}

// Round 16
// 330.172 us; speedup vs baseline: 1.3107x; 1.0796x over previous
//
#include <hip/hip_runtime.h>
#include <math.h>

#define NN 50000
#define EE 800000
#define GG 256
#define NPB 100          // nodes per bucket (<128 so local idx fits in 7 bits)
#define NBUCK 500        // NN / NPB exactly
#define EPB 4096         // edges per block chunk (hist/scatter)
#define NEB 196          // ceil(EE/EPB)
#define NB_NODE 196      // ceil(NN/256) node-parallel grids

__device__ __forceinline__ float gelu_f(float v){
    return 0.5f * v * (1.0f + erff(v * 0.70710678118654752f));
}

// ---------------- bucket histogram of dst (LDS-privatized, padded global) ----------------
__global__ __launch_bounds__(256) void k_hist(const int* __restrict__ dst, int* __restrict__ bucket_cnt_p, int e){
    __shared__ int hist[512];
    int t = threadIdx.x;
    int start = blockIdx.x * EPB;
    for (int k = t; k < 512; k += 256) hist[k] = 0;
    __syncthreads();
#pragma unroll
    for (int k = 0; k < EPB / 256; k++){
        int idx = start + k * 256 + t;
        if (idx < e) atomicAdd(&hist[dst[idx] / NPB], 1);
    }
    __syncthreads();
    for (int k = t; k < NBUCK; k += 256){
        int h = hist[k];
        if (h) atomicAdd(&bucket_cnt_p[k * 16], h);   // *16: one cache line per bucket
    }
}

// ---------------- scan bucket counts -> offsets + scatter cursors ----------------
__global__ __launch_bounds__(512) void k_bscan(const int* __restrict__ bucket_cnt_p,
                                               int* __restrict__ bucket_off, int* __restrict__ cursor_p){
    __shared__ int s[512];
    int t = threadIdx.x;
    int v = (t < NBUCK) ? bucket_cnt_p[t * 16] : 0;
    s[t] = v;
    __syncthreads();
    for (int off = 1; off < 512; off <<= 1){
        int u = (t >= off) ? s[t - off] : 0;
        __syncthreads();
        s[t] += u;
        __syncthreads();
    }
    if (t < NBUCK){
        int ex = s[t] - v;
        bucket_off[t] = ex;
        cursor_p[t * 16] = ex;
    }
}

// ---------------- partition packed (src<<7 | dst%NPB) into bucket-contiguous ebuf ----------------
__global__ __launch_bounds__(256) void k_scatter(const int* __restrict__ src, const int* __restrict__ dst,
                                                 int* __restrict__ cursor_p, int* __restrict__ ebuf, int e){
    __shared__ int hist[512], base[512];
    int t = threadIdx.x;
    int start = blockIdx.x * EPB;
    for (int k = t; k < 512; k += 256) hist[k] = 0;
    __syncthreads();
    int pk[EPB / 256], bb[EPB / 256];
    int cntl = 0;
#pragma unroll
    for (int k = 0; k < EPB / 256; k++){
        int idx = start + k * 256 + t;
        if (idx < e){
            int s_ = src[idx], d_ = dst[idx];
            int b_ = d_ / NPB;
            pk[cntl] = (s_ << 7) | (d_ - b_ * NPB);
            bb[cntl] = b_;
            atomicAdd(&hist[b_], 1);
            cntl++;
        }
    }
    __syncthreads();
    for (int k = t; k < NBUCK; k += 256){
        int h = hist[k];
        base[k] = h ? atomicAdd(&cursor_p[k * 16], h) : 0;
    }
    __syncthreads();
    for (int k = t; k < 512; k += 256) hist[k] = 0;
    __syncthreads();
    for (int k = 0; k < cntl; k++){
        int b_ = bb[k];
        int pos = base[b_] + atomicAdd(&hist[b_], 1);
        ebuf[pos] = pk[k];
    }
}

// ---------------- per-bucket CSR finalize: rp/col + dis/invdis/xd (LDS only) ----------------
__global__ __launch_bounds__(256) void k_build(const int* __restrict__ ebuf,
                                               const int* __restrict__ bucket_cnt_p,
                                               const int* __restrict__ bucket_off,
                                               int* __restrict__ rp, int* __restrict__ col,
                                               float* __restrict__ dis, float* __restrict__ invdis,
                                               float2* __restrict__ xd,
                                               const float* __restrict__ x, int n){
    int b = blockIdx.x;
    int t = threadIdx.x;
    int nbase = b * NPB;
    int eoff = bucket_off[b];
    int ecnt = bucket_cnt_p[b * 16];
    __shared__ int cnt[128], excl[128], cnt2[128], s[128];
    if (t < 128){ cnt[t] = 0; cnt2[t] = 0; }
    __syncthreads();
    for (int j = t; j < ecnt; j += 256)
        atomicAdd(&cnt[ebuf[eoff + j] & 127], 1);
    __syncthreads();
    int v = (t < 128) ? cnt[t] : 0;
    if (t < 128) s[t] = v;
    __syncthreads();
    for (int off = 1; off < 128; off <<= 1){
        int u = (t < 128 && t >= off) ? s[t - off] : 0;
        __syncthreads();
        if (t < 128) s[t] += u;
        __syncthreads();
    }
    if (t < 128) excl[t] = s[t] - v;
    __syncthreads();
    if (t < NPB){
        int node = nbase + t;      // NBUCK*NPB == NN exactly
        int dgg = cnt[t];
        rp[node] = eoff + excl[t];
        float dv = rsqrtf((float)(dgg + 1));   // +1 self loop
        dis[node] = dv;
        invdis[node] = sqrtf((float)(dgg + 1));
        xd[node] = make_float2(dv * x[node], dv);   // (xs, dis) packed
    }
    if (b == NBUCK - 1 && t == 0) rp[n] = eoff + ecnt;   // == E
    __syncthreads();
    for (int j = t; j < ecnt; j += 256){
        int v2 = ebuf[eoff + j];
        int li = v2 & 127;
        int p = eoff + excl[li] + atomicAdd(&cnt2[li], 1);
        col[p] = v2 >> 7;          // 6.4KB window per bucket -> full line reuse
    }
}

// ---------------- fused: CSR walk (agg xs, dsum) + layer-1 1->16 linear+GELU+prescale ----------------
__global__ __launch_bounds__(256) void k_g1l1(const float2* __restrict__ xd,
                                              const int* __restrict__ rp, const int* __restrict__ col,
                                              const float* __restrict__ W, const float* __restrict__ bias,
                                              float* __restrict__ dsum, float* __restrict__ hs, int n){
    int node = blockIdx.x * 256 + threadIdx.x;
    if (node >= n) return;
    int beg = rp[node], end = rp[node + 1];
    float a0 = 0.f, a1 = 0.f, d0 = 0.f, d1 = 0.f;
    int j = beg;
    for (; j + 1 < end; j += 2){
        float2 v0 = xd[col[j]];
        float2 v1 = xd[col[j + 1]];
        a0 += v0.x; d0 += v0.y;
        a1 += v1.x; d1 += v1.y;
    }
    if (j < end){ float2 v0 = xd[col[j]]; a0 += v0.x; d0 += v0.y; }
    float2 self = xd[node];
    float dn = self.y;
    dsum[node] = d0 + d1 + dn;
    float a = dn * (a0 + a1 + self.x);
    float4* o = (float4*)(hs + (size_t)node * 16);
#pragma unroll
    for (int u = 0; u < 4; u++){
        float4 r;
        r.x = gelu_f(bias[u*4+0] + a * W[u*4+0]) * dn;
        r.y = gelu_f(bias[u*4+1] + a * W[u*4+1]) * dn;
        r.z = gelu_f(bias[u*4+2] + a * W[u*4+2]) * dn;
        r.w = gelu_f(bias[u*4+3] + a * W[u*4+3]) * dn;
        o[u] = r;
    }
}

// ---------------- FUSED gather(+BN affine) -> LDS -> linear(+GELU,+prescale) ----------------
// Gather phase: CIN/8 threads per node, 8 channels each; BN'd aggregated row written to LDS.
// Lin phase: 4-node x 4-channel register tile; a and W both read from LDS.
// F2: CIN=16 COUT=32 (128 nodes/blk, 10KB) | F3: 32,64 (64, 16KB) | F4: 64,128 (32, 40KB)
template<int CIN, int COUT, bool SCALE>
__global__ __launch_bounds__(256) void k_gl(const float* __restrict__ hs_in, const int* __restrict__ rp,
                                            const int* __restrict__ col, const float* __restrict__ dis,
                                            const float* __restrict__ dsum, const float* __restrict__ stat,
                                            const float* __restrict__ gamma, const float* __restrict__ beta,
                                            const float* __restrict__ W, const float* __restrict__ bias,
                                            float* __restrict__ hs_out, int n){
    constexpr int TPN = CIN / 8;      // gather threads per node
    constexpr int NB  = 256 / TPN;    // nodes per block
    constexpr int KF  = CIN / 4;      // float4 per input row
    constexpr int QF  = COUT / 4;     // float4 per output row
    __shared__ float4 WL[CIN * QF];
    __shared__ float4 aL[NB * KF];
    int t = threadIdx.x;
    for (int idx = t; idx < CIN * QF; idx += 256)
        WL[idx] = ((const float4*)W)[idx];

    // ---- gather phase ----
    int nl = t / TPN, q8 = t % TPN;
    int q2 = q8 * 2;                  // first of two float4 slots
    int node = blockIdx.x * NB + nl;
    if (node < n){
        int c0 = q8 * 8;
        const float invn = 1.0f / (float)NN;
        float scv[8], shv[8];
#pragma unroll
        for (int u = 0; u < 8; u++){
            float mean = stat[c0 + u] * invn;
            float var  = stat[128 + c0 + u] * invn - mean * mean;
            float sc   = gamma[c0 + u] * rsqrtf(var + 1e-5f);
            scv[u] = sc;
            shv[u] = beta[c0 + u] - mean * sc;
        }
        const float4* h4 = (const float4*)hs_in;
        int beg = rp[node], end = rp[node + 1];
        float sa0=0.f,sa1=0.f,sa2=0.f,sa3=0.f, sb0=0.f,sb1=0.f,sb2=0.f,sb3=0.f;
        int j = beg;
        for (; j + 3 < end; j += 4){
            int i0 = col[j], i1 = col[j+1], i2 = col[j+2], i3 = col[j+3];
            float4 va0 = h4[i0 * KF + q2], vb0 = h4[i0 * KF + q2 + 1];
            float4 va1 = h4[i1 * KF + q2], vb1 = h4[i1 * KF + q2 + 1];
            float4 va2 = h4[i2 * KF + q2], vb2 = h4[i2 * KF + q2 + 1];
            float4 va3 = h4[i3 * KF + q2], vb3 = h4[i3 * KF + q2 + 1];
            sa0 += va0.x + va2.x; sa1 += va0.y + va2.y; sa2 += va0.z + va2.z; sa3 += va0.w + va2.w;
            sb0 += vb0.x + vb2.x; sb1 += vb0.y + vb2.y; sb2 += vb0.z + vb2.z; sb3 += vb0.w + vb2.w;
            sa0 += va1.x + va3.x; sa1 += va1.y + va3.y; sa2 += va1.z + va3.z; sa3 += va1.w + va3.w;
            sb0 += vb1.x + vb3.x; sb1 += vb1.y + vb3.y; sb2 += vb1.z + vb3.z; sb3 += vb1.w + vb3.w;
        }
        for (; j < end; j++){
            int i0 = col[j];
            float4 va = h4[i0 * KF + q2], vb = h4[i0 * KF + q2 + 1];
            sa0 += va.x; sa1 += va.y; sa2 += va.z; sa3 += va.w;
            sb0 += vb.x; sb1 += vb.y; sb2 += vb.z; sb3 += vb.w;
        }
        float4 vsa = h4[node * KF + q2], vsb = h4[node * KF + q2 + 1];  // self loop
        sa0 += vsa.x; sa1 += vsa.y; sa2 += vsa.z; sa3 += vsa.w;
        sb0 += vsb.x; sb1 += vsb.y; sb2 += vsb.z; sb3 += vsb.w;
        float dn  = dis[node];
        float dsm = dsum[node];
        aL[nl * KF + q2]     = make_float4((sa0*scv[0]+shv[0]*dsm)*dn, (sa1*scv[1]+shv[1]*dsm)*dn,
                                           (sa2*scv[2]+shv[2]*dsm)*dn, (sa3*scv[3]+shv[3]*dsm)*dn);
        aL[nl * KF + q2 + 1] = make_float4((sb0*scv[4]+shv[4]*dsm)*dn, (sb1*scv[5]+shv[5]*dsm)*dn,
                                           (sb2*scv[6]+shv[6]*dsm)*dn, (sb3*scv[7]+shv[7]*dsm)*dn);
    }
    __syncthreads();

    // ---- lin phase: 4 nodes x 4 channels per thread, operands from LDS ----
    int ng = t / QF, qg = t % QF;
    int n0l = ng * 4;
    int n0 = blockIdx.x * NB + n0l;
    float4 bb = ((const float4*)bias)[qg];
    float acc[4][4];
#pragma unroll
    for (int nd = 0; nd < 4; nd++){
        acc[nd][0] = bb.x; acc[nd][1] = bb.y; acc[nd][2] = bb.z; acc[nd][3] = bb.w;
    }
#pragma unroll 1
    for (int k4 = 0; k4 < KF; k4++){
        float4 xv[4];
#pragma unroll
        for (int nd = 0; nd < 4; nd++) xv[nd] = aL[(n0l + nd) * KF + k4];
        float4 w0 = WL[(k4 * 4 + 0) * QF + qg];
        float4 w1 = WL[(k4 * 4 + 1) * QF + qg];
        float4 w2 = WL[(k4 * 4 + 2) * QF + qg];
        float4 w3 = WL[(k4 * 4 + 3) * QF + qg];
#pragma unroll
        for (int nd = 0; nd < 4; nd++){
            acc[nd][0] += xv[nd].x*w0.x + xv[nd].y*w1.x + xv[nd].z*w2.x + xv[nd].w*w3.x;
            acc[nd][1] += xv[nd].x*w0.y + xv[nd].y*w1.y + xv[nd].z*w2.y + xv[nd].w*w3.y;
            acc[nd][2] += xv[nd].x*w0.z + xv[nd].y*w1.z + xv[nd].z*w2.z + xv[nd].w*w3.z;
            acc[nd][3] += xv[nd].x*w0.w + xv[nd].y*w1.w + xv[nd].z*w2.w + xv[nd].w*w3.w;
        }
    }
    float4* o4 = (float4*)hs_out;
#pragma unroll
    for (int nd = 0; nd < 4; nd++){
        int onode = n0 + nd;
        if (onode < n){
            float sc = SCALE ? dis[onode] : 1.0f;
            o4[(size_t)onode * QF + qg] =
                make_float4(gelu_f(acc[nd][0])*sc, gelu_f(acc[nd][1])*sc,
                            gelu_f(acc[nd][2])*sc, gelu_f(acc[nd][3])*sc);
        }
    }
}

// ---------------- BN stats over raw h (de-scale pre-scaled hs by invdis) ----------------
template<int C>
__global__ __launch_bounds__(256) void k_stats(const float* __restrict__ hs, const float* __restrict__ invdis,
                                               float* __restrict__ stat, int n){
    constexpr int REP = 256 / C;
    int t = threadIdx.x;
    int rep = t / C;
    int c = t % C;
    float s = 0.f, q = 0.f;
    for (int row = blockIdx.x * REP + rep; row < n; row += gridDim.x * REP){
        float v = hs[(long long)row * C + c] * invdis[row];
        s += v; q += v * v;
    }
    __shared__ float ss[256], sq[256];
    ss[t] = s; sq[t] = q;
    __syncthreads();
    for (int off = 128; off >= C; off >>= 1){
        if (t < off){ ss[t] += ss[t + off]; sq[t] += sq[t + off]; }
        __syncthreads();
    }
    if (t < C){
        atomicAdd(&stat[t], ss[t]);
        atomicAdd(&stat[128 + t], sq[t]);
    }
}

// ---------------- mean-pool: one block per graph, binary search sorted batch, no atomics ----------------
__global__ __launch_bounds__(128) void k_pool(const float* __restrict__ h4, const int* __restrict__ batch,
                                              float* __restrict__ pool, int n){
    int g = blockIdx.x;
    int t = threadIdx.x;
    int lo = 0, hi = n;
    while (lo < hi){ int mid = (lo + hi) >> 1; if (batch[mid] < g) lo = mid + 1; else hi = mid; }
    int s = lo;
    hi = n;
    while (lo < hi){ int mid = (lo + hi) >> 1; if (batch[mid] < g + 1) lo = mid + 1; else hi = mid; }
    int e = lo;
    float a0 = 0.f, a1 = 0.f, a2 = 0.f, a3 = 0.f;
    int node = s;
    for (; node + 3 < e; node += 4){
        a0 += h4[(size_t)(node + 0) * 128 + t];
        a1 += h4[(size_t)(node + 1) * 128 + t];
        a2 += h4[(size_t)(node + 2) * 128 + t];
        a3 += h4[(size_t)(node + 3) * 128 + t];
    }
    for (; node < e; node++) a0 += h4[(size_t)node * 128 + t];
    float sum = (a0 + a1) + (a2 + a3);
    pool[g * 128 + t] = sum / fmaxf((float)(e - s), 1.0f);
}

// ---------------- MLP head: 256 graphs, one block each ----------------
__global__ __launch_bounds__(128) void k_mlp(const float* __restrict__ pool,
                                             const float* __restrict__ yex,
                                             const float* __restrict__ lw1, const float* __restrict__ lb1,
                                             const float* __restrict__ lw2, const float* __restrict__ lb2,
                                             const float* __restrict__ lw3, const float* __restrict__ lb3,
                                             const float* __restrict__ lw4, const float* __restrict__ lb4,
                                             float* __restrict__ outp){
    int g = blockIdx.x;
    int t = threadIdx.x;
    __shared__ float z[136];
    __shared__ float z2[128];
    __shared__ float z3[64];
    __shared__ float z4[32];
    z[t] = pool[g * 128 + t];
    if (t < 7) z[128 + t] = yex[g * 7 + t];
    __syncthreads();
    {   // 135 -> 128
        float acc = lb1[t];
        for (int k = 0; k < 135; k++) acc += z[k] * lw1[k * 128 + t];
        z2[t] = gelu_f(acc);
    }
    __syncthreads();
    if (t < 64){   // 128 -> 64
        float acc = lb2[t];
        for (int k = 0; k < 128; k++) acc += z2[k] * lw2[k * 64 + t];
        z3[t] = gelu_f(acc);
    }
    __syncthreads();
    if (t < 32){   // 64 -> 32
        float acc = lb3[t];
        for (int k = 0; k < 64; k++) acc += z3[k] * lw3[k * 32 + t];
        z4[t] = gelu_f(acc);
    }
    __syncthreads();
    if (t < 2){    // 32 -> 2, sigmoid
        float acc = lb4[t];
        for (int k = 0; k < 32; k++) acc += z4[k] * lw4[k * 2 + t];
        outp[g * 2 + t] = 1.0f / (1.0f + expf(-acc));
    }
}

extern "C" void kernel_launch(void* const* d_in, const int* in_sizes, int n_in,
                              void* d_out, int out_size, void* d_ws, size_t ws_size,
                              hipStream_t stream) {
    const float* x     = (const float*)d_in[0];
    const int*   ei    = (const int*)  d_in[1];   // [2, E]: src = ei, dst = ei+E
    const int*   batch = (const int*)  d_in[2];
    const float* yex   = (const float*)d_in[3];
    const float* W1 = (const float*)d_in[4];  const float* b1 = (const float*)d_in[5];
    const float* W2 = (const float*)d_in[6];  const float* b2 = (const float*)d_in[7];
    const float* W3 = (const float*)d_in[8];  const float* b3 = (const float*)d_in[9];
    const float* W4 = (const float*)d_in[10]; const float* b4 = (const float*)d_in[11];
    const float* g1 = (const float*)d_in[12]; const float* be1 = (const float*)d_in[13];
    const float* g2 = (const float*)d_in[14]; const float* be2 = (const float*)d_in[15];
    const float* g3 = (const float*)d_in[16]; const float* be3 = (const float*)d_in[17];
    const float* lw1 = (const float*)d_in[18]; const float* lb1 = (const float*)d_in[19];
    const float* lw2 = (const float*)d_in[20]; const float* lb2 = (const float*)d_in[21];
    const float* lw3 = (const float*)d_in[22]; const float* lb3 = (const float*)d_in[23];
    const float* lw4 = (const float*)d_in[24]; const float* lb4 = (const float*)d_in[25];
    float* out = (float*)d_out;

    // ---- workspace carve (256B-aligned); zero-region first ----
    char* wsb = (char*)d_ws;
    size_t off = 0;
    auto alloc = [&](size_t elems) -> void* {
        void* p = wsb + off;
        off += ((elems * 4 + 255) / 256) * 256;
        return p;
    };
    float* stats        = (float*)alloc(3 * 256);      // layer l: [l*256+c]=sum, [+128]=sumsq
    int*   bucket_cnt_p = (int*)  alloc(NBUCK * 16);   // padded: 1 line per bucket
    size_t zero_bytes = off;
    int*   bucket_off   = (int*)  alloc(NBUCK);
    int*   cursor_p     = (int*)  alloc(NBUCK * 16);
    int*   ebuf         = (int*)  alloc(EE);           // packed (src<<7 | dst%NPB)
    float* pool   = (float*)alloc(GG * 128);
    int*   rp     = (int*)  alloc(NN + 1);
    float* dis    = (float*)alloc(NN);
    float* invdis = (float*)alloc(NN);
    float* dsum   = (float*)alloc(NN);
    float2* xd    = (float2*)alloc(NN * 2);            // (xs, dis) packed
    int*   col    = (int*)  alloc(EE);
    float* hbufA  = (float*)alloc((size_t)NN * 64);   // hs1 (16ch), hs3 (64ch)
    float* hbufB  = (float*)alloc((size_t)NN * 128);  // hs2 (32ch), h4 (128ch)

    hipMemsetAsync(d_ws, 0, zero_bytes, stream);

    // ---- CSR build via LDS-binned radix partition (no global random scatter) ----
    k_hist   <<<NEB, 256, 0, stream>>>(ei + EE, bucket_cnt_p, EE);
    k_bscan  <<<1, 512, 0, stream>>>(bucket_cnt_p, bucket_off, cursor_p);
    k_scatter<<<NEB, 256, 0, stream>>>(ei, ei + EE, cursor_p, ebuf, EE);
    k_build  <<<NBUCK, 256, 0, stream>>>(ebuf, bucket_cnt_p, bucket_off, rp, col, dis, invdis, xd, x, NN);

    // ---- layer 1: fused CSR-walk (agg xs + dsum) + 1->16 linear+gelu (pre-scaled), stats ----
    k_g1l1<<<NB_NODE, 256, 0, stream>>>(xd, rp, col, W1, b1, dsum, hbufA, NN);
    k_stats<16><<<128, 256, 0, stream>>>(hbufA, invdis, stats + 0, NN);

    // ---- layer 2: fused gather(BN1)+16->32 lin (pre-scaled out), stats ----
    k_gl<16, 32, true><<<(NN + 127) / 128, 256, 0, stream>>>(hbufA, rp, col, dis, dsum, stats + 0,
                                                             g1, be1, W2, b2, hbufB, NN);
    k_stats<32><<<128, 256, 0, stream>>>(hbufB, invdis, stats + 256, NN);

    // ---- layer 3: fused gather(BN2)+32->64 lin (pre-scaled out), stats ----
    k_gl<32, 64, true><<<(NN + 63) / 64, 256, 0, stream>>>(hbufB, rp, col, dis, dsum, stats + 256,
                                                           g2, be2, W3, b3, hbufA, NN);
    k_stats<64><<<128, 256, 0, stream>>>(hbufA, invdis, stats + 512, NN);

    // ---- layer 4: fused gather(BN3)+64->128 lin (raw out), streaming mean pool ----
    k_gl<64, 128, false><<<(NN + 31) / 32, 256, 0, stream>>>(hbufA, rp, col, dis, dsum, stats + 512,
                                                             g3, be3, W4, b4, hbufB, NN);
    k_pool<<<GG, 128, 0, stream>>>(hbufB, batch, pool, NN);

    // ---- MLP head ----
    k_mlp<<<GG, 128, 0, stream>>>(pool, yex,
                                  lw1, lb1, lw2, lb2, lw3, lb3, lw4, lb4, out);
}

// Round 17
// 317.520 us; speedup vs baseline: 1.3629x; 1.0398x over previous
//
#include <hip/hip_runtime.h>
#include <hip/hip_fp16.h>
#include <math.h>

#define NN 50000
#define EE 800000
#define GG 256
#define NPB 100          // nodes per bucket (<128 so local idx fits in 7 bits)
#define NBUCK 500        // NN / NPB exactly
#define EPB 4096         // edges per block chunk (hist/scatter)
#define NEB 196          // ceil(EE/EPB)
#define NB_NODE 196      // ceil(NN/256) node-parallel grids

__device__ __forceinline__ float gelu_f(float v){
    return 0.5f * v * (1.0f + erff(v * 0.70710678118654752f));
}

__device__ __forceinline__ unsigned pack2(float a, float b){
    __half2 h = __floats2half2_rn(a, b);
    return *reinterpret_cast<unsigned*>(&h);
}
__device__ __forceinline__ float2 up2(unsigned u){
    __half2 h = *reinterpret_cast<__half2*>(&u);
    return __half22float2(h);
}
__device__ __forceinline__ void acc8(const uint4 v, float* s){
    float2 f;
    f = up2(v.x); s[0] += f.x; s[1] += f.y;
    f = up2(v.y); s[2] += f.x; s[3] += f.y;
    f = up2(v.z); s[4] += f.x; s[5] += f.y;
    f = up2(v.w); s[6] += f.x; s[7] += f.y;
}

// ---------------- bucket histogram of dst (LDS-privatized, padded global) ----------------
__global__ __launch_bounds__(256) void k_hist(const int* __restrict__ dst, int* __restrict__ bucket_cnt_p, int e){
    __shared__ int hist[512];
    int t = threadIdx.x;
    int start = blockIdx.x * EPB;
    for (int k = t; k < 512; k += 256) hist[k] = 0;
    __syncthreads();
#pragma unroll
    for (int k = 0; k < EPB / 256; k++){
        int idx = start + k * 256 + t;
        if (idx < e) atomicAdd(&hist[dst[idx] / NPB], 1);
    }
    __syncthreads();
    for (int k = t; k < NBUCK; k += 256){
        int h = hist[k];
        if (h) atomicAdd(&bucket_cnt_p[k * 16], h);   // *16: one cache line per bucket
    }
}

// ---------------- scan bucket counts -> offsets + scatter cursors ----------------
__global__ __launch_bounds__(512) void k_bscan(const int* __restrict__ bucket_cnt_p,
                                               int* __restrict__ bucket_off, int* __restrict__ cursor_p){
    __shared__ int s[512];
    int t = threadIdx.x;
    int v = (t < NBUCK) ? bucket_cnt_p[t * 16] : 0;
    s[t] = v;
    __syncthreads();
    for (int off = 1; off < 512; off <<= 1){
        int u = (t >= off) ? s[t - off] : 0;
        __syncthreads();
        s[t] += u;
        __syncthreads();
    }
    if (t < NBUCK){
        int ex = s[t] - v;
        bucket_off[t] = ex;
        cursor_p[t * 16] = ex;
    }
}

// ---------------- partition packed (src<<7 | dst%NPB) into bucket-contiguous ebuf ----------------
__global__ __launch_bounds__(256) void k_scatter(const int* __restrict__ src, const int* __restrict__ dst,
                                                 int* __restrict__ cursor_p, int* __restrict__ ebuf, int e){
    __shared__ int hist[512], base[512];
    int t = threadIdx.x;
    int start = blockIdx.x * EPB;
    for (int k = t; k < 512; k += 256) hist[k] = 0;
    __syncthreads();
    int pk[EPB / 256], bb[EPB / 256];
    int cntl = 0;
#pragma unroll
    for (int k = 0; k < EPB / 256; k++){
        int idx = start + k * 256 + t;
        if (idx < e){
            int s_ = src[idx], d_ = dst[idx];
            int b_ = d_ / NPB;
            pk[cntl] = (s_ << 7) | (d_ - b_ * NPB);
            bb[cntl] = b_;
            atomicAdd(&hist[b_], 1);
            cntl++;
        }
    }
    __syncthreads();
    for (int k = t; k < NBUCK; k += 256){
        int h = hist[k];
        base[k] = h ? atomicAdd(&cursor_p[k * 16], h) : 0;
    }
    __syncthreads();
    for (int k = t; k < 512; k += 256) hist[k] = 0;
    __syncthreads();
    for (int k = 0; k < cntl; k++){
        int b_ = bb[k];
        int pos = base[b_] + atomicAdd(&hist[b_], 1);
        ebuf[pos] = pk[k];
    }
}

// ---------------- per-bucket CSR finalize: rp/col + dis/invdis/xd (LDS only) ----------------
__global__ __launch_bounds__(256) void k_build(const int* __restrict__ ebuf,
                                               const int* __restrict__ bucket_cnt_p,
                                               const int* __restrict__ bucket_off,
                                               int* __restrict__ rp, int* __restrict__ col,
                                               float* __restrict__ dis, float* __restrict__ invdis,
                                               float2* __restrict__ xd,
                                               const float* __restrict__ x, int n){
    int b = blockIdx.x;
    int t = threadIdx.x;
    int nbase = b * NPB;
    int eoff = bucket_off[b];
    int ecnt = bucket_cnt_p[b * 16];
    __shared__ int cnt[128], excl[128], cnt2[128], s[128];
    if (t < 128){ cnt[t] = 0; cnt2[t] = 0; }
    __syncthreads();
    for (int j = t; j < ecnt; j += 256)
        atomicAdd(&cnt[ebuf[eoff + j] & 127], 1);
    __syncthreads();
    int v = (t < 128) ? cnt[t] : 0;
    if (t < 128) s[t] = v;
    __syncthreads();
    for (int off = 1; off < 128; off <<= 1){
        int u = (t < 128 && t >= off) ? s[t - off] : 0;
        __syncthreads();
        if (t < 128) s[t] += u;
        __syncthreads();
    }
    if (t < 128) excl[t] = s[t] - v;
    __syncthreads();
    if (t < NPB){
        int node = nbase + t;      // NBUCK*NPB == NN exactly
        int dgg = cnt[t];
        rp[node] = eoff + excl[t];
        float dv = rsqrtf((float)(dgg + 1));   // +1 self loop
        dis[node] = dv;
        invdis[node] = sqrtf((float)(dgg + 1));
        xd[node] = make_float2(dv * x[node], dv);   // (xs, dis) packed
    }
    if (b == NBUCK - 1 && t == 0) rp[n] = eoff + ecnt;   // == E
    __syncthreads();
    for (int j = t; j < ecnt; j += 256){
        int v2 = ebuf[eoff + j];
        int li = v2 & 127;
        int p = eoff + excl[li] + atomicAdd(&cnt2[li], 1);
        col[p] = v2 >> 7;          // 6.4KB window per bucket -> full line reuse
    }
}

// ---------------- fused: CSR walk (agg xs, dsum) + layer-1 1->16 linear+GELU+prescale (fp16 out) ----------------
__global__ __launch_bounds__(256) void k_g1l1(const float2* __restrict__ xd,
                                              const int* __restrict__ rp, const int* __restrict__ col,
                                              const float* __restrict__ W, const float* __restrict__ bias,
                                              float* __restrict__ dsum, uint4* __restrict__ hs, int n){
    int node = blockIdx.x * 256 + threadIdx.x;
    if (node >= n) return;
    int beg = rp[node], end = rp[node + 1];
    float a0 = 0.f, a1 = 0.f, d0 = 0.f, d1 = 0.f;
    int j = beg;
    for (; j + 1 < end; j += 2){
        float2 v0 = xd[col[j]];
        float2 v1 = xd[col[j + 1]];
        a0 += v0.x; d0 += v0.y;
        a1 += v1.x; d1 += v1.y;
    }
    if (j < end){ float2 v0 = xd[col[j]]; a0 += v0.x; d0 += v0.y; }
    float2 self = xd[node];
    float dn = self.y;
    dsum[node] = d0 + d1 + dn;
    float a = dn * (a0 + a1 + self.x);
    float h[16];
#pragma unroll
    for (int u = 0; u < 16; u++) h[u] = gelu_f(bias[u] + a * W[u]) * dn;
    hs[node * 2 + 0] = make_uint4(pack2(h[0],h[1]),  pack2(h[2],h[3]),
                                  pack2(h[4],h[5]),  pack2(h[6],h[7]));
    hs[node * 2 + 1] = make_uint4(pack2(h[8],h[9]),  pack2(h[10],h[11]),
                                  pack2(h[12],h[13]), pack2(h[14],h[15]));
}

// ---------------- FUSED gather(fp16 in, +BN affine) -> LDS -> linear(+GELU, fp16/f32 out) ----------------
// Gather: CIN/8 threads per node, one uint4 (8 halves) per neighbor each.
// Lin: 4-node x 4-channel register tile from LDS. SCALE=true layers emit fp16 (prescaled);
// the final layer (SCALE=false) emits f32 h4 for the pool.
template<int CIN, int COUT, bool SCALE>
__global__ __launch_bounds__(256) void k_gl(const void* __restrict__ hs_in, const int* __restrict__ rp,
                                            const int* __restrict__ col, const float* __restrict__ dis,
                                            const float* __restrict__ dsum, const float* __restrict__ stat,
                                            const float* __restrict__ gamma, const float* __restrict__ beta,
                                            const float* __restrict__ W, const float* __restrict__ bias,
                                            void* __restrict__ hs_out, int n){
    constexpr int TPN = CIN / 8;      // gather threads per node (= uint4 per row)
    constexpr int NB  = 256 / TPN;    // nodes per block
    constexpr int KF  = CIN / 4;      // float4 per LDS row
    constexpr int QF  = COUT / 4;     // 4-channel groups per output row
    __shared__ float4 WL[CIN * QF];
    __shared__ float4 aL[NB * KF];
    int t = threadIdx.x;
    for (int idx = t; idx < CIN * QF; idx += 256)
        WL[idx] = ((const float4*)W)[idx];

    // ---- gather phase ----
    int nl = t / TPN, q8 = t % TPN;
    int node = blockIdx.x * NB + nl;
    if (node < n){
        int c0 = q8 * 8;
        const float invn = 1.0f / (float)NN;
        float scv[8], shv[8];
#pragma unroll
        for (int u = 0; u < 8; u++){
            float mean = stat[c0 + u] * invn;
            float var  = stat[128 + c0 + u] * invn - mean * mean;
            float sc   = gamma[c0 + u] * rsqrtf(var + 1e-5f);
            scv[u] = sc;
            shv[u] = beta[c0 + u] - mean * sc;
        }
        const uint4* h8 = (const uint4*)hs_in;
        int beg = rp[node], end = rp[node + 1];
        float sa[8] = {0.f,0.f,0.f,0.f,0.f,0.f,0.f,0.f};
        float sb[8] = {0.f,0.f,0.f,0.f,0.f,0.f,0.f,0.f};
        int j = beg;
        for (; j + 3 < end; j += 4){
            int i0 = col[j], i1 = col[j+1], i2 = col[j+2], i3 = col[j+3];
            uint4 v0 = h8[i0 * TPN + q8];
            uint4 v1 = h8[i1 * TPN + q8];
            uint4 v2 = h8[i2 * TPN + q8];
            uint4 v3 = h8[i3 * TPN + q8];
            acc8(v0, sa); acc8(v1, sb); acc8(v2, sa); acc8(v3, sb);
        }
        for (; j < end; j++) acc8(h8[col[j] * TPN + q8], sa);
        acc8(h8[node * TPN + q8], sa);    // self loop (weight 1 in pre-scaled space)
        float dn  = dis[node];
        float dsm = dsum[node];
#pragma unroll
        for (int u = 0; u < 8; u++) sa[u] += sb[u];
        aL[nl * KF + q8 * 2]     = make_float4((sa[0]*scv[0]+shv[0]*dsm)*dn, (sa[1]*scv[1]+shv[1]*dsm)*dn,
                                               (sa[2]*scv[2]+shv[2]*dsm)*dn, (sa[3]*scv[3]+shv[3]*dsm)*dn);
        aL[nl * KF + q8 * 2 + 1] = make_float4((sa[4]*scv[4]+shv[4]*dsm)*dn, (sa[5]*scv[5]+shv[5]*dsm)*dn,
                                               (sa[6]*scv[6]+shv[6]*dsm)*dn, (sa[7]*scv[7]+shv[7]*dsm)*dn);
    }
    __syncthreads();

    // ---- lin phase: 4 nodes x 4 channels per thread, operands from LDS ----
    int ng = t / QF, qg = t % QF;
    int n0l = ng * 4;
    int n0 = blockIdx.x * NB + n0l;
    float4 bb = ((const float4*)bias)[qg];
    float acc[4][4];
#pragma unroll
    for (int nd = 0; nd < 4; nd++){
        acc[nd][0] = bb.x; acc[nd][1] = bb.y; acc[nd][2] = bb.z; acc[nd][3] = bb.w;
    }
#pragma unroll 1
    for (int k4 = 0; k4 < KF; k4++){
        float4 xv[4];
#pragma unroll
        for (int nd = 0; nd < 4; nd++) xv[nd] = aL[(n0l + nd) * KF + k4];
        float4 w0 = WL[(k4 * 4 + 0) * QF + qg];
        float4 w1 = WL[(k4 * 4 + 1) * QF + qg];
        float4 w2 = WL[(k4 * 4 + 2) * QF + qg];
        float4 w3 = WL[(k4 * 4 + 3) * QF + qg];
#pragma unroll
        for (int nd = 0; nd < 4; nd++){
            acc[nd][0] += xv[nd].x*w0.x + xv[nd].y*w1.x + xv[nd].z*w2.x + xv[nd].w*w3.x;
            acc[nd][1] += xv[nd].x*w0.y + xv[nd].y*w1.y + xv[nd].z*w2.y + xv[nd].w*w3.y;
            acc[nd][2] += xv[nd].x*w0.z + xv[nd].y*w1.z + xv[nd].z*w2.z + xv[nd].w*w3.z;
            acc[nd][3] += xv[nd].x*w0.w + xv[nd].y*w1.w + xv[nd].z*w2.w + xv[nd].w*w3.w;
        }
    }
#pragma unroll
    for (int nd = 0; nd < 4; nd++){
        int onode = n0 + nd;
        if (onode < n){
            if (SCALE){   // fp16 pre-scaled output for the next gather
                float sc = dis[onode];
                float g0 = gelu_f(acc[nd][0]) * sc, g1 = gelu_f(acc[nd][1]) * sc;
                float g2 = gelu_f(acc[nd][2]) * sc, g3 = gelu_f(acc[nd][3]) * sc;
                ((uint2*)hs_out)[(size_t)onode * QF + qg] = make_uint2(pack2(g0, g1), pack2(g2, g3));
            } else {      // f32 h4 output for the pool
                ((float4*)hs_out)[(size_t)onode * QF + qg] =
                    make_float4(gelu_f(acc[nd][0]), gelu_f(acc[nd][1]),
                                gelu_f(acc[nd][2]), gelu_f(acc[nd][3]));
            }
        }
    }
}

// ---------------- BN stats over raw h (decode fp16, de-scale by invdis) ----------------
template<int C>
__global__ __launch_bounds__(256) void k_stats(const void* __restrict__ hs, const float* __restrict__ invdis,
                                               float* __restrict__ stat, int n){
    constexpr int REP = 256 / C;
    int t = threadIdx.x;
    int rep = t / C;
    int c = t % C;
    const __half* hh = (const __half*)hs;
    float s = 0.f, q = 0.f;
    for (int row = blockIdx.x * REP + rep; row < n; row += gridDim.x * REP){
        float v = __half2float(hh[(long long)row * C + c]) * invdis[row];
        s += v; q += v * v;
    }
    __shared__ float ss[256], sq[256];
    ss[t] = s; sq[t] = q;
    __syncthreads();
    for (int off = 128; off >= C; off >>= 1){
        if (t < off){ ss[t] += ss[t + off]; sq[t] += sq[t + off]; }
        __syncthreads();
    }
    if (t < C){
        atomicAdd(&stat[t], ss[t]);
        atomicAdd(&stat[128 + t], sq[t]);
    }
}

// ---------------- mean-pool: one block per graph, binary search sorted batch, no atomics ----------------
__global__ __launch_bounds__(128) void k_pool(const float* __restrict__ h4, const int* __restrict__ batch,
                                              float* __restrict__ pool, int n){
    int g = blockIdx.x;
    int t = threadIdx.x;
    int lo = 0, hi = n;
    while (lo < hi){ int mid = (lo + hi) >> 1; if (batch[mid] < g) lo = mid + 1; else hi = mid; }
    int s = lo;
    hi = n;
    while (lo < hi){ int mid = (lo + hi) >> 1; if (batch[mid] < g + 1) lo = mid + 1; else hi = mid; }
    int e = lo;
    float a0 = 0.f, a1 = 0.f, a2 = 0.f, a3 = 0.f;
    int node = s;
    for (; node + 3 < e; node += 4){
        a0 += h4[(size_t)(node + 0) * 128 + t];
        a1 += h4[(size_t)(node + 1) * 128 + t];
        a2 += h4[(size_t)(node + 2) * 128 + t];
        a3 += h4[(size_t)(node + 3) * 128 + t];
    }
    for (; node < e; node++) a0 += h4[(size_t)node * 128 + t];
    float sum = (a0 + a1) + (a2 + a3);
    pool[g * 128 + t] = sum / fmaxf((float)(e - s), 1.0f);
}

// ---------------- MLP head: 256 graphs, one block each ----------------
__global__ __launch_bounds__(128) void k_mlp(const float* __restrict__ pool,
                                             const float* __restrict__ yex,
                                             const float* __restrict__ lw1, const float* __restrict__ lb1,
                                             const float* __restrict__ lw2, const float* __restrict__ lb2,
                                             const float* __restrict__ lw3, const float* __restrict__ lb3,
                                             const float* __restrict__ lw4, const float* __restrict__ lb4,
                                             float* __restrict__ outp){
    int g = blockIdx.x;
    int t = threadIdx.x;
    __shared__ float z[136];
    __shared__ float z2[128];
    __shared__ float z3[64];
    __shared__ float z4[32];
    z[t] = pool[g * 128 + t];
    if (t < 7) z[128 + t] = yex[g * 7 + t];
    __syncthreads();
    {   // 135 -> 128
        float acc = lb1[t];
        for (int k = 0; k < 135; k++) acc += z[k] * lw1[k * 128 + t];
        z2[t] = gelu_f(acc);
    }
    __syncthreads();
    if (t < 64){   // 128 -> 64
        float acc = lb2[t];
        for (int k = 0; k < 128; k++) acc += z2[k] * lw2[k * 64 + t];
        z3[t] = gelu_f(acc);
    }
    __syncthreads();
    if (t < 32){   // 64 -> 32
        float acc = lb3[t];
        for (int k = 0; k < 64; k++) acc += z3[k] * lw3[k * 32 + t];
        z4[t] = gelu_f(acc);
    }
    __syncthreads();
    if (t < 2){    // 32 -> 2, sigmoid
        float acc = lb4[t];
        for (int k = 0; k < 32; k++) acc += z4[k] * lw4[k * 2 + t];
        outp[g * 2 + t] = 1.0f / (1.0f + expf(-acc));
    }
}

extern "C" void kernel_launch(void* const* d_in, const int* in_sizes, int n_in,
                              void* d_out, int out_size, void* d_ws, size_t ws_size,
                              hipStream_t stream) {
    const float* x     = (const float*)d_in[0];
    const int*   ei    = (const int*)  d_in[1];   // [2, E]: src = ei, dst = ei+E
    const int*   batch = (const int*)  d_in[2];
    const float* yex   = (const float*)d_in[3];
    const float* W1 = (const float*)d_in[4];  const float* b1 = (const float*)d_in[5];
    const float* W2 = (const float*)d_in[6];  const float* b2 = (const float*)d_in[7];
    const float* W3 = (const float*)d_in[8];  const float* b3 = (const float*)d_in[9];
    const float* W4 = (const float*)d_in[10]; const float* b4 = (const float*)d_in[11];
    const float* g1 = (const float*)d_in[12]; const float* be1 = (const float*)d_in[13];
    const float* g2 = (const float*)d_in[14]; const float* be2 = (const float*)d_in[15];
    const float* g3 = (const float*)d_in[16]; const float* be3 = (const float*)d_in[17];
    const float* lw1 = (const float*)d_in[18]; const float* lb1 = (const float*)d_in[19];
    const float* lw2 = (const float*)d_in[20]; const float* lb2 = (const float*)d_in[21];
    const float* lw3 = (const float*)d_in[22]; const float* lb3 = (const float*)d_in[23];
    const float* lw4 = (const float*)d_in[24]; const float* lb4 = (const float*)d_in[25];
    float* out = (float*)d_out;

    // ---- workspace carve (256B-aligned); zero-region first ----
    char* wsb = (char*)d_ws;
    size_t off = 0;
    auto alloc = [&](size_t elems) -> void* {
        void* p = wsb + off;
        off += ((elems * 4 + 255) / 256) * 256;
        return p;
    };
    float* stats        = (float*)alloc(3 * 256);      // layer l: [l*256+c]=sum, [+128]=sumsq
    int*   bucket_cnt_p = (int*)  alloc(NBUCK * 16);   // padded: 1 line per bucket
    size_t zero_bytes = off;
    int*   bucket_off   = (int*)  alloc(NBUCK);
    int*   cursor_p     = (int*)  alloc(NBUCK * 16);
    int*   ebuf         = (int*)  alloc(EE);           // packed (src<<7 | dst%NPB)
    float* pool   = (float*)alloc(GG * 128);
    int*   rp     = (int*)  alloc(NN + 1);
    float* dis    = (float*)alloc(NN);
    float* invdis = (float*)alloc(NN);
    float* dsum   = (float*)alloc(NN);
    float2* xd    = (float2*)alloc(NN * 2);            // (xs, dis) packed
    int*   col    = (int*)  alloc(EE);
    void*  hbufA  = alloc((size_t)NN * 32);   // fp16 hs1 (32B/node), fp16 hs3 (128B/node)
    void*  hbufB  = alloc((size_t)NN * 128);  // fp16 hs2 (64B/node), f32 h4 (512B/node)

    hipMemsetAsync(d_ws, 0, zero_bytes, stream);

    // ---- CSR build via LDS-binned radix partition (no global random scatter) ----
    k_hist   <<<NEB, 256, 0, stream>>>(ei + EE, bucket_cnt_p, EE);
    k_bscan  <<<1, 512, 0, stream>>>(bucket_cnt_p, bucket_off, cursor_p);
    k_scatter<<<NEB, 256, 0, stream>>>(ei, ei + EE, cursor_p, ebuf, EE);
    k_build  <<<NBUCK, 256, 0, stream>>>(ebuf, bucket_cnt_p, bucket_off, rp, col, dis, invdis, xd, x, NN);

    // ---- layer 1: fused CSR-walk (agg xs + dsum) + 1->16 linear+gelu (fp16 pre-scaled), stats ----
    k_g1l1<<<NB_NODE, 256, 0, stream>>>(xd, rp, col, W1, b1, dsum, (uint4*)hbufA, NN);
    k_stats<16><<<128, 256, 0, stream>>>(hbufA, invdis, stats + 0, NN);

    // ---- layer 2: fused gather(BN1)+16->32 lin (fp16 pre-scaled out), stats ----
    k_gl<16, 32, true><<<(NN + 127) / 128, 256, 0, stream>>>(hbufA, rp, col, dis, dsum, stats + 0,
                                                             g1, be1, W2, b2, hbufB, NN);
    k_stats<32><<<128, 256, 0, stream>>>(hbufB, invdis, stats + 256, NN);

    // ---- layer 3: fused gather(BN2)+32->64 lin (fp16 pre-scaled out), stats ----
    k_gl<32, 64, true><<<(NN + 63) / 64, 256, 0, stream>>>(hbufB, rp, col, dis, dsum, stats + 256,
                                                           g2, be2, W3, b3, hbufA, NN);
    k_stats<64><<<128, 256, 0, stream>>>(hbufA, invdis, stats + 512, NN);

    // ---- layer 4: fused gather(BN3)+64->128 lin (f32 out), streaming mean pool ----
    k_gl<64, 128, false><<<(NN + 31) / 32, 256, 0, stream>>>(hbufA, rp, col, dis, dsum, stats + 512,
                                                             g3, be3, W4, b4, hbufB, NN);
    k_pool<<<GG, 128, 0, stream>>>((const float*)hbufB, batch, pool, NN);

    // ---- MLP head ----
    k_mlp<<<GG, 128, 0, stream>>>(pool, yex,
                                  lw1, lb1, lw2, lb2, lw3, lb3, lw4, lb4, out);
}